// Round 4
// baseline (268.716 us; speedup 1.0000x reference)
//
#include <hip/hip_runtime.h>
#include <hip/hip_bf16.h>
#include <stdint.h>

// Problem constants (T=128, B=64, H=1024)
#define TT 128
#define BB 64
#define HH 1024
#define MM (TT * BB)          // 8192 rows of the two GEMMs
#define NLANE (BB * HH)       // 65536 scan lanes
#define DELTA 1.0e-4          // flag band; bf16 3-pass worst-tail ~6e-5 (1.7x margin) — do NOT shrink
#define F16_ONE 0x3C00        // _Float16 1.0

typedef __attribute__((ext_vector_type(8))) short bf16x8;
typedef __attribute__((ext_vector_type(8))) _Float16 f16x8;
typedef __attribute__((ext_vector_type(4))) float f32x4;

// async global->LDS, 16 B per lane; LDS dest = wave-uniform base + lane*16
#define GLOAD16(g, l)                                                        \
    __builtin_amdgcn_global_load_lds(                                        \
        (const __attribute__((address_space(1))) unsigned int*)(g),          \
        (__attribute__((address_space(3))) unsigned int*)(l), 16, 0, 0)

#define FENCE() __builtin_amdgcn_sched_barrier(0)

static __device__ __forceinline__ unsigned short bf16_bits(float f) {
    __hip_bfloat16 b = __float2bfloat16(f);
    return *reinterpret_cast<unsigned short*>(&b);
}
static __device__ __forceinline__ unsigned short f16_bits(float f) {
    _Float16 h = (_Float16)f;
    return *reinterpret_cast<unsigned short*>(&h);
}

// ---------------------------------------------------------------------------
// Fused prep — writes K-concat layouts.
//   A2[8192][2048] = [Xhi | Xlo] per row;  B2[1024][2048] = [W1hi | W1lo].
// ---------------------------------------------------------------------------
__global__ __launch_bounds__(256) void prep_fused(const float* __restrict__ x,
                                                  const float* __restrict__ W1,
                                                  const float* __restrict__ W2,
                                                  unsigned short* __restrict__ A2,
                                                  unsigned short* __restrict__ B2,
                                                  unsigned short* __restrict__ w2h,
                                                  int* __restrict__ cnt) {
    const int bid = blockIdx.x;
    if (bid == 0 && threadIdx.x == 0) *cnt = 0;

    if (bid < 9216) {
        const bool isX = (bid < 8192);
        const int i = (isX ? bid : bid - 8192) * 256 + threadIdx.x;
        const float4 v4 = reinterpret_cast<const float4*>(isX ? x : W1)[i];
        float v[4] = {v4.x, v4.y, v4.z, v4.w};
        unsigned short hb[4], lb[4];
#pragma unroll
        for (int c = 0; c < 4; c++) {
            hb[c] = bf16_bits(v[c]);
            __hip_bfloat16 hh = *reinterpret_cast<__hip_bfloat16*>(&hb[c]);
            lb[c] = bf16_bits(v[c] - __bfloat162float(hh));
        }
        ushort4* dst = reinterpret_cast<ushort4*>(isX ? A2 : B2);
        const int r = i >> 8;          // row (1024 cols = 256 ushort4)
        const int c4 = i & 255;
        dst[(size_t)r * 512 + c4]       = make_ushort4(hb[0], hb[1], hb[2], hb[3]);
        dst[(size_t)r * 512 + 256 + c4] = make_ushort4(lb[0], lb[1], lb[2], lb[3]);
    } else {
        const int i = (bid - 9216) * 256 + threadIdx.x;
        const float4 v4 = reinterpret_cast<const float4*>(W2)[i];
        float v[4] = {v4.x, v4.y, v4.z, v4.w};
        unsigned short hb[4];
#pragma unroll
        for (int c = 0; c < 4; c++) hb[c] = f16_bits(v[c]);
        reinterpret_cast<ushort4*>(w2h)[i] = make_ushort4(hb[0], hb[1], hb[2], hb[3]);
    }
}

// ---------------------------------------------------------------------------
// GEMM1 — R13: A-only LDS (triple-buffered, 96 KB) + B fragments loaded
// GLOBAL->REGISTER (double-buffered named sets, static indices).  Rationale
// (R12 post-mortem): LDS port was critical (1920cy/tile vs 1033cy MFMA).
// Removing B from LDS cuts DS to ~1024cy/tile — balanced with MFMA.
//   - virtual K=3072 over A2/B2 concat (== 3-pass split-bf16), 48 tiles BK=64
//   - per tile: 4 A-stage gloads (t+2) + 8 B reg-loads (t+1); ONE vmcnt(12)
//     + ONE s_barrier per tile.  Ledger: 12 newest may fly => B(t), A(t+1)
//     proven landed at the wait.
//   - B loads are inline-asm global_load_dwordx4 (saddr form) so compiler
//     vmcnt bookkeeping never mixes with ours; every wait is followed by
//     sched_barrier(0) (rule #18).
// ---------------------------------------------------------------------------
__global__ __launch_bounds__(512, 2) void gemm1_breg(const unsigned short* __restrict__ A2,
                                                     const unsigned short* __restrict__ B2,
                                                     float* __restrict__ C) {
    __shared__ short As_[3][256 * 64];   // 96 KB

    const int tid = threadIdx.x;
    const int lane = tid & 63;
    const int wave = tid >> 6;       // 0..7
    const int wr = wave >> 1;        // 0..3  (M quarter: 64 rows)
    const int wc = wave & 1;         // 0..1  (N half: 64 cols)

    // XCD-grouped decode: blocks with same bid%8 form one XCD group of 32.
    const int bid = blockIdx.x;
    const int orig = (bid & 7) * 32 + (bid >> 3);
    const int m0 = (orig >> 3) * 256;
    const int n0 = (orig & 7) * 128;

    const int rsel = lane & 15;
    const int part = lane >> 4;      // 0..3

    // A fragment LDS addresses (shorts), buffer-relative; row = 64 shorts =
    // 8 slots of 16B; swizzle: slot' = slot ^ (row & 7)
    int adrA[4][2];
#pragma unroll
    for (int mi = 0; mi < 4; mi++) {
        const int ra = wr * 64 + mi * 16 + rsel;
#pragma unroll
        for (int ks = 0; ks < 2; ks++) {
            const int slot = ks * 4 + part;
            adrA[mi][ks] = ra * 64 + ((slot ^ (ra & 7)) << 3);
        }
    }

    // A staging: one 8KB chunk (64 rows x 128B) per GLOAD16; global source
    // pre-swizzled so LDS write stays linear.
    const int srow = tid >> 3;                    // 0..63
    const int gslot8 = ((tid & 7) ^ (srow & 7)) << 3;
    const int ldso = wave * 512;                  // wave-uniform (shorts)

#define STAGE_A(buf, q, kcol)                                                     \
    GLOAD16(&A2[(size_t)(m0 + (q) * 64 + srow) * 2048 + (kcol) + gslot8],         \
            &As_[buf][(q) * 4096 + ldso])

    // B register-load setup: lane fragment = B2[n0 + wc*64 + ni*16 + (lane&15)]
    //                                          [kB + (ks*4 + (lane>>4))*8 .. +8]
    // byte voffset = ((wc*64 + rsel)*2048 + part*8)*2 + ni*65536 + kB*2 (+ks*64 imm)
    const unsigned short* sbase = B2 + (size_t)n0 * 2048;   // wave-uniform
    int voffNi[4];
    {
        const int vbase = (((wc * 64 + rsel) * 2048) + part * 8) * 2;
#pragma unroll
        for (int ni = 0; ni < 4; ni++) voffNi[ni] = vbase + ni * 65536;
    }

    // 8 asm loads for one tile's B into named set S (static indices only)
#define LOADB(S, kb2)                                                             \
    do {                                                                          \
        int _v0 = voffNi[0] + (kb2);                                              \
        int _v1 = voffNi[1] + (kb2);                                              \
        int _v2 = voffNi[2] + (kb2);                                              \
        int _v3 = voffNi[3] + (kb2);                                              \
        asm volatile("global_load_dwordx4 %0, %1, %2 offset:0"  : "=&v"(S[0][0]) : "v"(_v0), "s"(sbase)); \
        asm volatile("global_load_dwordx4 %0, %1, %2 offset:64" : "=&v"(S[0][1]) : "v"(_v0), "s"(sbase)); \
        asm volatile("global_load_dwordx4 %0, %1, %2 offset:0"  : "=&v"(S[1][0]) : "v"(_v1), "s"(sbase)); \
        asm volatile("global_load_dwordx4 %0, %1, %2 offset:64" : "=&v"(S[1][1]) : "v"(_v1), "s"(sbase)); \
        asm volatile("global_load_dwordx4 %0, %1, %2 offset:0"  : "=&v"(S[2][0]) : "v"(_v2), "s"(sbase)); \
        asm volatile("global_load_dwordx4 %0, %1, %2 offset:64" : "=&v"(S[2][1]) : "v"(_v2), "s"(sbase)); \
        asm volatile("global_load_dwordx4 %0, %1, %2 offset:0"  : "=&v"(S[3][0]) : "v"(_v3), "s"(sbase)); \
        asm volatile("global_load_dwordx4 %0, %1, %2 offset:64" : "=&v"(S[3][1]) : "v"(_v3), "s"(sbase)); \
    } while (0)

    // k -> concat-column maps (uniform within a 64-wide tile)
#define KA_OF(t) (((t) < 16) ? (t) * 64 : (t) * 64 - 1024)
#define KB_OF(t) (((t) < 32) ? (t) * 64 : (t) * 64 - 2048)

    bf16x8 bs0[4][2], bs1[4][2];
    f32x4 acc[4][4] = {};

    // ---- prologue: A(0) x4, B(0)->set0 x8, A(1) x4  (16 issues) ----
    STAGE_A(0, 0, 0); STAGE_A(0, 1, 0); STAGE_A(0, 2, 0); STAGE_A(0, 3, 0);
    LOADB(bs0, 0);
    STAGE_A(1, 0, 64); STAGE_A(1, 1, 64); STAGE_A(1, 2, 64); STAGE_A(1, 3, 64);
    asm volatile("s_waitcnt vmcnt(12)" ::: "memory");   // A(0) landed
    FENCE();
    __builtin_amdgcn_s_barrier();
    FENCE();

    // ---- tile body: uses set SU, loads B(t+1) into SL ----
#define TILE(t_, SU, SL)                                                          \
    do {                                                                          \
        const int t = (t_);                                                       \
        const short* As = As_[t % 3];                                             \
        const int sbuf = (t + 2) % 3;                                             \
        const int tc = (t + 2 < 48) ? t + 2 : 47;   /* clamp tail (dead data) */  \
        const int kA2 = KA_OF(tc);                                                \
        const int tb = (t + 1 < 48) ? t + 1 : 47;                                 \
        const int kB1 = KB_OF(tb) * 2;                                            \
        bf16x8 a[4][2];                                                           \
        _Pragma("unroll")                                                         \
        for (int mi = 0; mi < 4; mi++) {                                          \
            a[mi][0] = *reinterpret_cast<const bf16x8*>(&As[adrA[mi][0]]);        \
            a[mi][1] = *reinterpret_cast<const bf16x8*>(&As[adrA[mi][1]]);        \
        }                                                                         \
        STAGE_A(sbuf, 0, kA2); STAGE_A(sbuf, 1, kA2);                             \
        STAGE_A(sbuf, 2, kA2); STAGE_A(sbuf, 3, kA2);                             \
        LOADB(SL, kB1);                                                           \
        asm volatile("s_waitcnt vmcnt(12)" ::: "memory"); /* B(t), A(t+1) in */   \
        FENCE();                                                                  \
        __builtin_amdgcn_s_barrier();                                             \
        FENCE();                                                                  \
        __builtin_amdgcn_s_setprio(1);                                            \
        _Pragma("unroll")                                                         \
        for (int mi = 0; mi < 4; mi++)                                            \
            _Pragma("unroll")                                                     \
            for (int ni = 0; ni < 4; ni++) {                                      \
                acc[mi][ni] = __builtin_amdgcn_mfma_f32_16x16x32_bf16(            \
                    a[mi][0], SU[ni][0], acc[mi][ni], 0, 0, 0);                   \
                acc[mi][ni] = __builtin_amdgcn_mfma_f32_16x16x32_bf16(            \
                    a[mi][1], SU[ni][1], acc[mi][ni], 0, 0, 0);                   \
            }                                                                     \
        __builtin_amdgcn_s_setprio(0);                                            \
    } while (0)

    for (int tp = 0; tp < 24; ++tp) {
        TILE(tp * 2,     bs0, bs1);
        TILE(tp * 2 + 1, bs1, bs0);
    }
#undef TILE
#undef STAGE_A
#undef LOADB

    asm volatile("s_waitcnt vmcnt(0)" ::: "memory");   // drain dead tail stages
    FENCE();

    // ---- epilogue: C write (16x16 C/D layout: col=lane&15, row=(lane>>4)*4+r)
    const int col = lane & 15;
    const int quad = lane >> 4;
#pragma unroll
    for (int mi = 0; mi < 4; mi++)
#pragma unroll
        for (int ni = 0; ni < 4; ni++) {
            const int m = m0 + wr * 64 + mi * 16 + quad * 4;
            const int n = n0 + wc * 64 + ni * 16 + col;
            float* dst = &C[(size_t)m * HH + n];
#pragma unroll
            for (int r = 0; r < 4; r++)
                dst[(size_t)r * HH] = acc[mi][ni][r];
        }
}

// ---------------------------------------------------------------------------
// LIF scan — unchanged.
// ---------------------------------------------------------------------------
__global__ __launch_bounds__(256) void lif_scan_flag(const float* __restrict__ xp,
                                                     unsigned short* __restrict__ sp,
                                                     int* __restrict__ count,
                                                     int* __restrict__ list) {
    const int idx = blockIdx.x * 256 + threadIdx.x;
    double v = 0.0;
    bool flg = false;
#pragma unroll 4
    for (int t = 0; t < TT; t++) {
        const double x = (double)xp[(size_t)t * NLANE + idx];
        const double h = v + (x - v) * 0.5;
        const bool s = (h >= 1.0);
        flg |= (fabs(h - 1.0) < DELTA);
        v = s ? 0.0 : h;
        sp[(size_t)t * NLANE + idx] = s ? (unsigned short)F16_ONE : (unsigned short)0;
    }
    if (flg) {
        const int i = atomicAdd(count, 1);
        list[i] = idx;
    }
}

// ---------------------------------------------------------------------------
// Fused exact-recompute — unchanged.
// ---------------------------------------------------------------------------
__global__ __launch_bounds__(1024) void recompute_fused(const float* __restrict__ X,
                                                        const float* __restrict__ W1,
                                                        const int* __restrict__ count,
                                                        const int* __restrict__ list,
                                                        unsigned short* __restrict__ sp) {
    __shared__ double hbuf[TT];
    const int cnt = *count;
    const int wv = threadIdx.x >> 6;   // 0..15
    const int ln = threadIdx.x & 63;

    for (int li = blockIdx.x; li < cnt; li += gridDim.x) {
        const int lane = list[li];
        const int b = lane >> 10;
        const int h = lane & (HH - 1);
        const float4* w4 = reinterpret_cast<const float4*>(W1 + (size_t)h * HH);

        for (int t = wv; t < TT; t += 16) {
            const float4* x4 = reinterpret_cast<const float4*>(X + (size_t)(t * BB + b) * HH);
            double s0 = 0.0, s1 = 0.0, s2 = 0.0, s3 = 0.0;
#pragma unroll
            for (int i = 0; i < 4; i++) {
                const float4 xa = x4[ln + i * 64];
                const float4 wa = w4[ln + i * 64];
                s0 = fma((double)xa.x, (double)wa.x, s0);
                s1 = fma((double)xa.y, (double)wa.y, s1);
                s2 = fma((double)xa.z, (double)wa.z, s2);
                s3 = fma((double)xa.w, (double)wa.w, s3);
            }
            double s = (s0 + s1) + (s2 + s3);
#pragma unroll
            for (int off = 32; off >= 1; off >>= 1)
                s += __shfl_down(s, off);
            if (ln == 0) hbuf[t] = s;
        }
        __syncthreads();

        if (threadIdx.x == 0) {
            double v = 0.0;
            for (int t = 0; t < TT; t++) {
                const double hh = v + (hbuf[t] - v) * 0.5;
                const bool s = (hh >= 1.0);
                v = s ? 0.0 : hh;
                sp[(size_t)t * NLANE + lane] = s ? (unsigned short)F16_ONE : (unsigned short)0;
            }
        }
        __syncthreads();
    }
}

// ---------------------------------------------------------------------------
// GEMM2 — unchanged (128x64 tile, grid-transposed for S m-tile L2 reuse).
// ---------------------------------------------------------------------------
__global__ __launch_bounds__(256) void gemm2_mfma(const unsigned short* __restrict__ S,
                                                  const unsigned short* __restrict__ W,
                                                  float* __restrict__ O) {
    __shared__ short As[128 * 32];   // 8 KB
    __shared__ short Bs[64 * 32];    // 4 KB

    const int tid = threadIdx.x;
    const int lane = tid & 63;
    const int wave = tid >> 6;
    const int m0 = blockIdx.y * 128;   // 64 blocks in M (slow axis)
    const int n0 = blockIdx.x * 64;    // 16 blocks in N (fast axis)
    const int wm = (wave >> 1) * 64;   // {0,64}
    const int wn = (wave & 1) * 32;    // {0,32}

    const int rsel = lane & 15;
    const int part = lane >> 4;

    int adrA[4], adrB[2];
#pragma unroll
    for (int i = 0; i < 4; i++) {
        const int ra = wm + i * 16 + rsel;
        adrA[i] = ra * 32 + (part ^ ((ra >> 1) & 3)) * 8;
    }
#pragma unroll
    for (int i = 0; i < 2; i++) {
        const int rb = wn + i * 16 + rsel;
        adrB[i] = rb * 32 + (part ^ ((rb >> 1) & 3)) * 8;
    }

    f32x4 acc[4][2] = {};

    for (int k0 = 0; k0 < HH; k0 += 32) {
        // 768 chunks: A = 0..511, B = 512..767; wave-uniform sides (64 | 256)
#pragma unroll
        for (int p = 0; p < 3; p++) {
            const int c = tid + p * 256;
            const int cb = wave * 64 + p * 256;
            if (c < 512) {
                const int row = c >> 2;
                const int pslot = c & 3;
                const int pdata = pslot ^ ((row >> 1) & 3);
                GLOAD16(&S[(size_t)(m0 + row) * HH + k0 + pdata * 8], &As[cb * 8]);
            } else {
                const int c2 = c - 512;
                const int row = c2 >> 2;
                const int pslot = c2 & 3;
                const int pdata = pslot ^ ((row >> 1) & 3);
                GLOAD16(&W[(size_t)(n0 + row) * HH + k0 + pdata * 8], &Bs[(cb - 512) * 8]);
            }
        }
        __syncthreads();

        f16x8 a[4], b[2];
#pragma unroll
        for (int mi = 0; mi < 4; mi++)
            a[mi] = *reinterpret_cast<f16x8*>(&As[adrA[mi]]);
#pragma unroll
        for (int ni = 0; ni < 2; ni++)
            b[ni] = *reinterpret_cast<f16x8*>(&Bs[adrB[ni]]);

#pragma unroll
        for (int mi = 0; mi < 4; mi++)
#pragma unroll
            for (int ni = 0; ni < 2; ni++)
                acc[mi][ni] = __builtin_amdgcn_mfma_f32_16x16x32_f16(
                    a[mi], b[ni], acc[mi][ni], 0, 0, 0);

        __syncthreads();
    }

    const int col = lane & 15;
    const int quad = lane >> 4;
#pragma unroll
    for (int mi = 0; mi < 4; mi++)
#pragma unroll
        for (int ni = 0; ni < 2; ni++) {
            const int m = m0 + wm + mi * 16 + quad * 4;
            const int n = n0 + wn + ni * 16 + col;
            float* dst = &O[(size_t)m * HH + n];
#pragma unroll
            for (int r = 0; r < 4; r++)
                dst[(size_t)r * HH] = acc[mi][ni][r];
        }
}

// ---------------------------------------------------------------------------
// Launch (5 dispatches)
// ---------------------------------------------------------------------------
extern "C" void kernel_launch(void* const* d_in, const int* in_sizes, int n_in,
                              void* d_out, int out_size, void* d_ws, size_t ws_size,
                              hipStream_t stream) {
    const float* x  = (const float*)d_in[0];
    const float* W1 = (const float*)d_in[1];
    const float* W2 = (const float*)d_in[2];
    float* out = (float*)d_out;

    char* ws = (char*)d_ws;

    unsigned short* A2   = (unsigned short*)ws;                 // 33.55 MB  [Xhi|Xlo] 8192x2048
    unsigned short* B2   = A2 + (size_t)MM * 2048;              //  4.19 MB  [W1hi|W1lo] 1024x2048
    unsigned short* w2h  = B2 + (size_t)HH * 2048;              //  2.10 MB
    int*            list = (int*)(w2h + (size_t)HH * HH);       // 256 KB
    int*            cnt  = list + NLANE;                        // 4 B
    float*          xp   = (float*)(((uintptr_t)(cnt + 64) + 255) & ~(uintptr_t)255); // 33.55 MB
    unsigned short* sp   = (unsigned short*)ws;  // overlay: spikes reuse A2 after gemm1

    prep_fused<<<10240, 256, 0, stream>>>(x, W1, W2, A2, B2, w2h, cnt);

    gemm1_breg<<<256, 512, 0, stream>>>(A2, B2, xp);

    lif_scan_flag<<<NLANE / 256, 256, 0, stream>>>(xp, sp, cnt, list);

    recompute_fused<<<512, 1024, 0, stream>>>(x, W1, cnt, list, sp);

    dim3 g2(HH / 64, MM / 128);   // x = N (fast): 16 consecutive blocks share an S m-tile
    gemm2_mfma<<<g2, 256, 0, stream>>>(sp, w2h, out);
}

// Round 6
// 222.761 us; speedup vs baseline: 1.2063x; 1.2063x over previous
//
#include <hip/hip_runtime.h>
#include <hip/hip_bf16.h>
#include <stdint.h>

// Problem constants (T=128, B=64, H=1024)
#define TT 128
#define BB 64
#define HH 1024
#define MM (TT * BB)          // 8192 rows of the two GEMMs
#define NLANE (BB * HH)       // 65536 scan lanes
#define DELTA 1.0e-4          // flag band; bf16 3-pass worst-tail ~6e-5 (1.7x margin) — do NOT shrink
#define F16_ONE 0x3C00        // _Float16 1.0

typedef __attribute__((ext_vector_type(8))) short bf16x8;
typedef __attribute__((ext_vector_type(8))) _Float16 f16x8;
typedef __attribute__((ext_vector_type(4))) float f32x4;

// async global->LDS, 16 B per lane; LDS dest = wave-uniform base + lane*16
#define GLOAD16(g, l)                                                        \
    __builtin_amdgcn_global_load_lds(                                        \
        (const __attribute__((address_space(1))) unsigned int*)(g),          \
        (__attribute__((address_space(3))) unsigned int*)(l), 16, 0, 0)

#define FENCE() __builtin_amdgcn_sched_barrier(0)

static __device__ __forceinline__ unsigned short bf16_bits(float f) {
    __hip_bfloat16 b = __float2bfloat16(f);
    return *reinterpret_cast<unsigned short*>(&b);
}
static __device__ __forceinline__ unsigned short f16_bits(float f) {
    _Float16 h = (_Float16)f;
    return *reinterpret_cast<unsigned short*>(&h);
}

// ---------------------------------------------------------------------------
// Fused prep — R15 (same as R14):
//   A2[8192][2048] = [Xhi | Xlo] per row.
//   Bf = FRAGMENT-READY B: Bf[tb][nt][ks][lane][8 shorts], tb=0..31
//        (tb 0..15 = W1hi cols tb*64.., tb 16..31 = W1lo cols (tb-16)*64..).
//        Fragment (tb,nt,ks): lane l holds W1{hi,lo}[nt*16 + (l&15)]
//        [ (tb%16)*64 + ks*32 + (l>>4)*8 .. +8 ] — exactly the MFMA B operand,
//        so a wave loads it as ONE coalesced 1KB global_load_dwordx4.
//   w2h f16 W2.
// ---------------------------------------------------------------------------
__global__ __launch_bounds__(256) void prep_fused(const float* __restrict__ x,
                                                  const float* __restrict__ W1,
                                                  const float* __restrict__ W2,
                                                  unsigned short* __restrict__ A2,
                                                  unsigned short* __restrict__ Bf,
                                                  unsigned short* __restrict__ w2h,
                                                  int* __restrict__ cnt) {
    const int bid = blockIdx.x;
    if (bid == 0 && threadIdx.x == 0) *cnt = 0;

    if (bid < 8192) {                       // ---- X -> A2 (hi|lo concat rows)
        const int i = bid * 256 + threadIdx.x;
        const float4 v4 = reinterpret_cast<const float4*>(x)[i];
        float v[4] = {v4.x, v4.y, v4.z, v4.w};
        unsigned short hb[4], lb[4];
#pragma unroll
        for (int c = 0; c < 4; c++) {
            hb[c] = bf16_bits(v[c]);
            __hip_bfloat16 hh = *reinterpret_cast<__hip_bfloat16*>(&hb[c]);
            lb[c] = bf16_bits(v[c] - __bfloat162float(hh));
        }
        ushort4* dst = reinterpret_cast<ushort4*>(A2);
        const int r = i >> 8;
        const int c4 = i & 255;
        dst[(size_t)r * 512 + c4]       = make_ushort4(hb[0], hb[1], hb[2], hb[3]);
        dst[(size_t)r * 512 + 256 + c4] = make_ushort4(lb[0], lb[1], lb[2], lb[3]);
    } else if (bid < 9216) {                // ---- W1 -> Bf fragment-ready
        const int i = (bid - 8192) * 256 + threadIdx.x;   // float4 idx over W1
        const float4 v4 = reinterpret_cast<const float4*>(W1)[i];
        float v[4] = {v4.x, v4.y, v4.z, v4.w};
        unsigned short hb[4], lb[4];
#pragma unroll
        for (int c = 0; c < 4; c++) {
            hb[c] = bf16_bits(v[c]);
            __hip_bfloat16 hh = *reinterpret_cast<__hip_bfloat16*>(&hb[c]);
            lb[c] = bf16_bits(v[c] - __bfloat162float(hh));
        }
        const int r  = i >> 8;               // W1 row (= GEMM n) 0..1023
        const int c0 = (i & 255) * 4;        // W1 col 0..1020 (step 4)
        const int tbh  = c0 >> 6;            // 0..15
        const int ks   = (c0 >> 5) & 1;
        const int p    = (c0 >> 3) & 3;
        const int e0   = c0 & 7;             // 0 or 4
        const int lane = p * 16 + (r & 15);
        const int nt   = r >> 4;
        const size_t ih = ((((size_t)tbh * 64 + nt) * 2 + ks) * 64 + lane) * 8 + e0;
        const size_t il = ((((size_t)(tbh + 16) * 64 + nt) * 2 + ks) * 64 + lane) * 8 + e0;
        *reinterpret_cast<ushort4*>(&Bf[ih]) = make_ushort4(hb[0], hb[1], hb[2], hb[3]);
        *reinterpret_cast<ushort4*>(&Bf[il]) = make_ushort4(lb[0], lb[1], lb[2], lb[3]);
    } else {                                // ---- W2 -> f16
        const int i = (bid - 9216) * 256 + threadIdx.x;
        const float4 v4 = reinterpret_cast<const float4*>(W2)[i];
        float v[4] = {v4.x, v4.y, v4.z, v4.w};
        unsigned short hb[4];
#pragma unroll
        for (int c = 0; c < 4; c++) hb[c] = f16_bits(v[c]);
        reinterpret_cast<ushort4*>(w2h)[i] = make_ushort4(hb[0], hb[1], hb[2], hb[3]);
    }
}

// ---------------------------------------------------------------------------
// GEMM1 — R15: R14 structure with the asm saddr fix: saddr is strictly
// workgroup-uniform (Bf + (n0>>4)*1024 + tbn*65536); the wave-dependent part
// (wc) lives in the per-lane VGPR voffset.  A in triple-buffered LDS (96 KB,
// pre-swizzled gload_lds) + B fragments loaded COALESCED global->register
// from fragment-ready Bf (1 KB contiguous per wave per fragment).
// Virtual K=3072 (3-pass split-bf16), 48 tiles BK=64.
//   - per tile: 4 A-stages (t+2) + 8 B reg-loads (t+1); ONE vmcnt(12) + ONE
//     barrier.  Ledger: at the wait, the 12 newest may fly => B(t) and A(t+1)
//     proven landed (order-insensitive within the fenced region).
//   - barrier AFTER the MFMA cluster (closes the buf-reuse race).
// ---------------------------------------------------------------------------
__global__ __launch_bounds__(512, 2) void gemm1_bf(const unsigned short* __restrict__ A2,
                                                   const unsigned short* __restrict__ Bf,
                                                   float* __restrict__ C) {
    __shared__ short As_[3][256 * 64];   // 96 KB

    const int tid = threadIdx.x;
    const int lane = tid & 63;
    const int wave = tid >> 6;       // 0..7
    const int wr = wave >> 1;        // 0..3  (M quarter: 64 rows)
    const int wc = wave & 1;         // 0..1  (N half: 64 cols)

    // XCD-grouped decode: blocks with same bid%8 form one XCD group of 32.
    const int bid = blockIdx.x;
    const int orig = (bid & 7) * 32 + (bid >> 3);
    const int m0 = (orig >> 3) * 256;
    const int n0 = (orig & 7) * 128;

    const int rsel = lane & 15;
    const int part = lane >> 4;      // 0..3

    // A fragment LDS addresses (shorts), buffer-relative; row = 64 shorts =
    // 8 slots of 16B; swizzle: slot' = slot ^ (row & 7)
    int adrA[4][2];
#pragma unroll
    for (int mi = 0; mi < 4; mi++) {
        const int ra = wr * 64 + mi * 16 + rsel;
#pragma unroll
        for (int ks = 0; ks < 2; ks++) {
            const int slot = ks * 4 + part;
            adrA[mi][ks] = ra * 64 + ((slot ^ (ra & 7)) << 3);
        }
    }

    // A staging: one 8KB chunk (64 rows x 128B) per GLOAD16; global source
    // pre-swizzled so LDS write stays linear.
    const int srow = tid >> 3;                    // 0..63
    const int gslot8 = ((tid & 7) ^ (srow & 7)) << 3;
    const int ldso = wave * 512;                  // wave-uniform (shorts)

#define STAGE_A(buf, q, kcol)                                                     \
    GLOAD16(&A2[(size_t)(m0 + (q) * 64 + srow) * 2048 + (kcol) + gslot8],         \
            &As_[buf][(q) * 4096 + ldso])

    // B: workgroup-uniform base (blockIdx only!); wave/lane parts in voffset.
    // voffset bytes = wc*8192 + ni*2048 + lane*16 ; ks via offset imm (0/1024).
    const unsigned short* Bf_u = Bf + ((size_t)(n0 >> 4)) * 1024;
    int voffNi[4];
#pragma unroll
    for (int ni = 0; ni < 4; ni++) voffNi[ni] = wc * 8192 + ni * 2048 + lane * 16;

#define LOADB(S, sb)                                                              \
    do {                                                                          \
        asm volatile("global_load_dwordx4 %0, %1, %2 offset:0"    : "=&v"(S[0][0]) : "v"(voffNi[0]), "s"(sb)); \
        asm volatile("global_load_dwordx4 %0, %1, %2 offset:1024" : "=&v"(S[0][1]) : "v"(voffNi[0]), "s"(sb)); \
        asm volatile("global_load_dwordx4 %0, %1, %2 offset:0"    : "=&v"(S[1][0]) : "v"(voffNi[1]), "s"(sb)); \
        asm volatile("global_load_dwordx4 %0, %1, %2 offset:1024" : "=&v"(S[1][1]) : "v"(voffNi[1]), "s"(sb)); \
        asm volatile("global_load_dwordx4 %0, %1, %2 offset:0"    : "=&v"(S[2][0]) : "v"(voffNi[2]), "s"(sb)); \
        asm volatile("global_load_dwordx4 %0, %1, %2 offset:1024" : "=&v"(S[2][1]) : "v"(voffNi[2]), "s"(sb)); \
        asm volatile("global_load_dwordx4 %0, %1, %2 offset:0"    : "=&v"(S[3][0]) : "v"(voffNi[3]), "s"(sb)); \
        asm volatile("global_load_dwordx4 %0, %1, %2 offset:1024" : "=&v"(S[3][1]) : "v"(voffNi[3]), "s"(sb)); \
    } while (0)

    // k -> concat-column map for A (uniform within a 64-wide tile)
#define KA_OF(t) (((t) < 16) ? (t) * 64 : (t) * 64 - 1024)

    bf16x8 bs0[4][2], bs1[4][2];
    f32x4 acc[4][4] = {};

    // ---- prologue: A(0) x4, B(0)->set0 x8, A(1) x4  (16 issues) ----
    STAGE_A(0, 0, 0); STAGE_A(0, 1, 0); STAGE_A(0, 2, 0); STAGE_A(0, 3, 0);
    LOADB(bs0, Bf_u);                               // tile 0 -> tb = 0
    STAGE_A(1, 0, 64); STAGE_A(1, 1, 64); STAGE_A(1, 2, 64); STAGE_A(1, 3, 64);
    asm volatile("s_waitcnt vmcnt(12)" ::: "memory");   // A(0) landed
    FENCE();
    __builtin_amdgcn_s_barrier();
    FENCE();

    // ---- tile body: uses set SU (loaded last tile), loads B(t+1) into SL ----
#define TILE(t_, SU, SL)                                                          \
    do {                                                                          \
        const int t = (t_);                                                       \
        const short* As = As_[t % 3];                                             \
        const int sbuf = (t + 2) % 3;                                             \
        const int tc = (t + 2 < 48) ? t + 2 : 47;   /* clamp tail (dead data) */  \
        const int kA2 = KA_OF(tc);                                                \
        const int tb1 = (t + 1 < 48) ? t + 1 : 47;                                \
        const int tbn = (tb1 < 32) ? tb1 : tb1 - 32;  /* pass-3 reuses hi tiles */\
        const unsigned short* sb = Bf_u + (size_t)tbn * 65536;                    \
        bf16x8 a[4][2];                                                           \
        _Pragma("unroll")                                                         \
        for (int mi = 0; mi < 4; mi++) {                                          \
            a[mi][0] = *reinterpret_cast<const bf16x8*>(&As[adrA[mi][0]]);        \
            a[mi][1] = *reinterpret_cast<const bf16x8*>(&As[adrA[mi][1]]);        \
        }                                                                         \
        STAGE_A(sbuf, 0, kA2); STAGE_A(sbuf, 1, kA2);                             \
        STAGE_A(sbuf, 2, kA2); STAGE_A(sbuf, 3, kA2);                             \
        LOADB(SL, sb);                                                            \
        asm volatile("s_waitcnt vmcnt(12)" ::: "memory"); /* B(t), A(t+1) in */   \
        FENCE();                                                                  \
        __builtin_amdgcn_s_setprio(1);                                            \
        _Pragma("unroll")                                                         \
        for (int mi = 0; mi < 4; mi++)                                            \
            _Pragma("unroll")                                                     \
            for (int ni = 0; ni < 4; ni++) {                                      \
                acc[mi][ni] = __builtin_amdgcn_mfma_f32_16x16x32_bf16(            \
                    a[mi][0], SU[ni][0], acc[mi][ni], 0, 0, 0);                   \
                acc[mi][ni] = __builtin_amdgcn_mfma_f32_16x16x32_bf16(            \
                    a[mi][1], SU[ni][1], acc[mi][ni], 0, 0, 0);                   \
            }                                                                     \
        __builtin_amdgcn_s_setprio(0);                                            \
        FENCE();                                                                  \
        __builtin_amdgcn_s_barrier();                                             \
        FENCE();                                                                  \
    } while (0)

    for (int tp = 0; tp < 24; ++tp) {
        TILE(tp * 2,     bs0, bs1);
        TILE(tp * 2 + 1, bs1, bs0);
    }
#undef TILE
#undef STAGE_A
#undef LOADB

    asm volatile("s_waitcnt vmcnt(0)" ::: "memory");   // drain dead tail stages
    FENCE();

    // ---- epilogue: C write (16x16 C/D layout: col=lane&15, row=(lane>>4)*4+r)
    const int col = lane & 15;
    const int quad = lane >> 4;
#pragma unroll
    for (int mi = 0; mi < 4; mi++)
#pragma unroll
        for (int ni = 0; ni < 4; ni++) {
            const int m = m0 + wr * 64 + mi * 16 + quad * 4;
            const int n = n0 + wc * 64 + ni * 16 + col;
            float* dst = &C[(size_t)m * HH + n];
#pragma unroll
            for (int r = 0; r < 4; r++)
                dst[(size_t)r * HH] = acc[mi][ni][r];
        }
}

// ---------------------------------------------------------------------------
// LIF scan — unchanged.
// ---------------------------------------------------------------------------
__global__ __launch_bounds__(256) void lif_scan_flag(const float* __restrict__ xp,
                                                     unsigned short* __restrict__ sp,
                                                     int* __restrict__ count,
                                                     int* __restrict__ list) {
    const int idx = blockIdx.x * 256 + threadIdx.x;
    double v = 0.0;
    bool flg = false;
#pragma unroll 4
    for (int t = 0; t < TT; t++) {
        const double x = (double)xp[(size_t)t * NLANE + idx];
        const double h = v + (x - v) * 0.5;
        const bool s = (h >= 1.0);
        flg |= (fabs(h - 1.0) < DELTA);
        v = s ? 0.0 : h;
        sp[(size_t)t * NLANE + idx] = s ? (unsigned short)F16_ONE : (unsigned short)0;
    }
    if (flg) {
        const int i = atomicAdd(count, 1);
        list[i] = idx;
    }
}

// ---------------------------------------------------------------------------
// Fused exact-recompute — unchanged.
// ---------------------------------------------------------------------------
__global__ __launch_bounds__(1024) void recompute_fused(const float* __restrict__ X,
                                                        const float* __restrict__ W1,
                                                        const int* __restrict__ count,
                                                        const int* __restrict__ list,
                                                        unsigned short* __restrict__ sp) {
    __shared__ double hbuf[TT];
    const int cnt = *count;
    const int wv = threadIdx.x >> 6;   // 0..15
    const int ln = threadIdx.x & 63;

    for (int li = blockIdx.x; li < cnt; li += gridDim.x) {
        const int lane = list[li];
        const int b = lane >> 10;
        const int h = lane & (HH - 1);
        const float4* w4 = reinterpret_cast<const float4*>(W1 + (size_t)h * HH);

        for (int t = wv; t < TT; t += 16) {
            const float4* x4 = reinterpret_cast<const float4*>(X + (size_t)(t * BB + b) * HH);
            double s0 = 0.0, s1 = 0.0, s2 = 0.0, s3 = 0.0;
#pragma unroll
            for (int i = 0; i < 4; i++) {
                const float4 xa = x4[ln + i * 64];
                const float4 wa = w4[ln + i * 64];
                s0 = fma((double)xa.x, (double)wa.x, s0);
                s1 = fma((double)xa.y, (double)wa.y, s1);
                s2 = fma((double)xa.z, (double)wa.z, s2);
                s3 = fma((double)xa.w, (double)wa.w, s3);
            }
            double s = (s0 + s1) + (s2 + s3);
#pragma unroll
            for (int off = 32; off >= 1; off >>= 1)
                s += __shfl_down(s, off);
            if (ln == 0) hbuf[t] = s;
        }
        __syncthreads();

        if (threadIdx.x == 0) {
            double v = 0.0;
            for (int t = 0; t < TT; t++) {
                const double hh = v + (hbuf[t] - v) * 0.5;
                const bool s = (hh >= 1.0);
                v = s ? 0.0 : hh;
                sp[(size_t)t * NLANE + lane] = s ? (unsigned short)F16_ONE : (unsigned short)0;
            }
        }
        __syncthreads();
    }
}

// ---------------------------------------------------------------------------
// GEMM2 — unchanged (128x64 tile, grid-transposed for S m-tile L2 reuse).
// ---------------------------------------------------------------------------
__global__ __launch_bounds__(256) void gemm2_mfma(const unsigned short* __restrict__ S,
                                                  const unsigned short* __restrict__ W,
                                                  float* __restrict__ O) {
    __shared__ short As[128 * 32];   // 8 KB
    __shared__ short Bs[64 * 32];    // 4 KB

    const int tid = threadIdx.x;
    const int lane = tid & 63;
    const int wave = tid >> 6;
    const int m0 = blockIdx.y * 128;   // 64 blocks in M (slow axis)
    const int n0 = blockIdx.x * 64;    // 16 blocks in N (fast axis)
    const int wm = (wave >> 1) * 64;   // {0,64}
    const int wn = (wave & 1) * 32;    // {0,32}

    const int rsel = lane & 15;
    const int part = lane >> 4;

    int adrA[4], adrB[2];
#pragma unroll
    for (int i = 0; i < 4; i++) {
        const int ra = wm + i * 16 + rsel;
        adrA[i] = ra * 32 + (part ^ ((ra >> 1) & 3)) * 8;
    }
#pragma unroll
    for (int i = 0; i < 2; i++) {
        const int rb = wn + i * 16 + rsel;
        adrB[i] = rb * 32 + (part ^ ((rb >> 1) & 3)) * 8;
    }

    f32x4 acc[4][2] = {};

    for (int k0 = 0; k0 < HH; k0 += 32) {
        // 768 chunks: A = 0..511, B = 512..767; wave-uniform sides (64 | 256)
#pragma unroll
        for (int p = 0; p < 3; p++) {
            const int c = tid + p * 256;
            const int cb = wave * 64 + p * 256;
            if (c < 512) {
                const int row = c >> 2;
                const int pslot = c & 3;
                const int pdata = pslot ^ ((row >> 1) & 3);
                GLOAD16(&S[(size_t)(m0 + row) * HH + k0 + pdata * 8], &As[cb * 8]);
            } else {
                const int c2 = c - 512;
                const int row = c2 >> 2;
                const int pslot = c2 & 3;
                const int pdata = pslot ^ ((row >> 1) & 3);
                GLOAD16(&W[(size_t)(n0 + row) * HH + k0 + pdata * 8], &Bs[(cb - 512) * 8]);
            }
        }
        __syncthreads();

        f16x8 a[4], b[2];
#pragma unroll
        for (int mi = 0; mi < 4; mi++)
            a[mi] = *reinterpret_cast<f16x8*>(&As[adrA[mi]]);
#pragma unroll
        for (int ni = 0; ni < 2; ni++)
            b[ni] = *reinterpret_cast<f16x8*>(&Bs[adrB[ni]]);

#pragma unroll
        for (int mi = 0; mi < 4; mi++)
#pragma unroll
            for (int ni = 0; ni < 2; ni++)
                acc[mi][ni] = __builtin_amdgcn_mfma_f32_16x16x32_f16(
                    a[mi], b[ni], acc[mi][ni], 0, 0, 0);

        __syncthreads();
    }

    const int col = lane & 15;
    const int quad = lane >> 4;
#pragma unroll
    for (int mi = 0; mi < 4; mi++)
#pragma unroll
        for (int ni = 0; ni < 2; ni++) {
            const int m = m0 + wm + mi * 16 + quad * 4;
            const int n = n0 + wn + ni * 16 + col;
            float* dst = &O[(size_t)m * HH + n];
#pragma unroll
            for (int r = 0; r < 4; r++)
                dst[(size_t)r * HH] = acc[mi][ni][r];
        }
}

// ---------------------------------------------------------------------------
// Launch (5 dispatches)
// ---------------------------------------------------------------------------
extern "C" void kernel_launch(void* const* d_in, const int* in_sizes, int n_in,
                              void* d_out, int out_size, void* d_ws, size_t ws_size,
                              hipStream_t stream) {
    const float* x  = (const float*)d_in[0];
    const float* W1 = (const float*)d_in[1];
    const float* W2 = (const float*)d_in[2];
    float* out = (float*)d_out;

    char* ws = (char*)d_ws;

    unsigned short* A2   = (unsigned short*)ws;                 // 33.55 MB  [Xhi|Xlo] 8192x2048
    unsigned short* Bf   = A2 + (size_t)MM * 2048;              //  4.19 MB  fragment-ready B (32 tiles)
    unsigned short* w2h  = Bf + (size_t)2048 * 1024;            //  2.10 MB
    int*            list = (int*)(w2h + (size_t)HH * HH);       // 256 KB
    int*            cnt  = list + NLANE;                        // 4 B
    float*          xp   = (float*)(((uintptr_t)(cnt + 64) + 255) & ~(uintptr_t)255); // 33.55 MB
    unsigned short* sp   = (unsigned short*)ws;  // overlay: spikes reuse A2 after gemm1

    prep_fused<<<10240, 256, 0, stream>>>(x, W1, W2, A2, Bf, w2h, cnt);

    gemm1_bf<<<256, 512, 0, stream>>>(A2, Bf, xp);

    lif_scan_flag<<<NLANE / 256, 256, 0, stream>>>(xp, sp, cnt, list);

    recompute_fused<<<512, 1024, 0, stream>>>(x, W1, cnt, list, sp);

    dim3 g2(HH / 64, MM / 128);   // x = N (fast): 16 consecutive blocks share an S m-tile
    gemm2_mfma<<<g2, 256, 0, stream>>>(sp, w2h, out);
}

// Round 7
// 213.260 us; speedup vs baseline: 1.2600x; 1.0446x over previous
//
#include <hip/hip_runtime.h>
#include <hip/hip_bf16.h>
#include <stdint.h>

// Problem constants (T=128, B=64, H=1024)
#define TT 128
#define BB 64
#define HH 1024
#define MM (TT * BB)          // 8192 rows of the two GEMMs
#define NLANE (BB * HH)       // 65536 scan lanes
#define DELTA 1.0e-4          // flag band; bf16 3-pass worst-tail ~6e-5 (1.7x margin) — do NOT shrink
#define F16_ONE 0x3C00        // _Float16 1.0

typedef __attribute__((ext_vector_type(8))) short bf16x8;
typedef __attribute__((ext_vector_type(8))) _Float16 f16x8;
typedef __attribute__((ext_vector_type(4))) float f32x4;

// async global->LDS, 16 B per lane; LDS dest = wave-uniform base + lane*16
#define GLOAD16(g, l)                                                        \
    __builtin_amdgcn_global_load_lds(                                        \
        (const __attribute__((address_space(1))) unsigned int*)(g),          \
        (__attribute__((address_space(3))) unsigned int*)(l), 16, 0, 0)

#define FENCE() __builtin_amdgcn_sched_barrier(0)

static __device__ __forceinline__ unsigned short bf16_bits(float f) {
    __hip_bfloat16 b = __float2bfloat16(f);
    return *reinterpret_cast<unsigned short*>(&b);
}
static __device__ __forceinline__ unsigned short f16_bits(float f) {
    _Float16 h = (_Float16)f;
    return *reinterpret_cast<unsigned short*>(&h);
}

// ---------------------------------------------------------------------------
// Fused prep — K-concat layouts (R12 version, proven):
//   A2[8192][2048] = [Xhi | Xlo] per row;  B2[1024][2048] = [W1hi | W1lo].
// ---------------------------------------------------------------------------
__global__ __launch_bounds__(256) void prep_fused(const float* __restrict__ x,
                                                  const float* __restrict__ W1,
                                                  const float* __restrict__ W2,
                                                  unsigned short* __restrict__ A2,
                                                  unsigned short* __restrict__ B2,
                                                  unsigned short* __restrict__ w2h,
                                                  int* __restrict__ cnt) {
    const int bid = blockIdx.x;
    if (bid == 0 && threadIdx.x == 0) *cnt = 0;

    if (bid < 9216) {
        const bool isX = (bid < 8192);
        const int i = (isX ? bid : bid - 8192) * 256 + threadIdx.x;
        const float4 v4 = reinterpret_cast<const float4*>(isX ? x : W1)[i];
        float v[4] = {v4.x, v4.y, v4.z, v4.w};
        unsigned short hb[4], lb[4];
#pragma unroll
        for (int c = 0; c < 4; c++) {
            hb[c] = bf16_bits(v[c]);
            __hip_bfloat16 hh = *reinterpret_cast<__hip_bfloat16*>(&hb[c]);
            lb[c] = bf16_bits(v[c] - __bfloat162float(hh));
        }
        ushort4* dst = reinterpret_cast<ushort4*>(isX ? A2 : B2);
        const int r = i >> 8;          // row (1024 cols = 256 ushort4)
        const int c4 = i & 255;
        dst[(size_t)r * 512 + c4]       = make_ushort4(hb[0], hb[1], hb[2], hb[3]);
        dst[(size_t)r * 512 + 256 + c4] = make_ushort4(lb[0], lb[1], lb[2], lb[3]);
    } else {
        const int i = (bid - 9216) * 256 + threadIdx.x;
        const float4 v4 = reinterpret_cast<const float4*>(W2)[i];
        float v[4] = {v4.x, v4.y, v4.z, v4.w};
        unsigned short hb[4];
#pragma unroll
        for (int c = 0; c < 4; c++) hb[c] = f16_bits(v[c]);
        reinterpret_cast<ushort4*>(w2h)[i] = make_ushort4(hb[0], hb[1], hb[2], hb[3]);
    }
}

// ---------------------------------------------------------------------------
// GEMM1 — R16: R12 (triple-buffered LDS, 64x64 wave tiles, one barrier +
// vmcnt(6) per tile) + HALF-TILE REGISTER PIPELINING.  R12 post-mortem showed
// ds_read port (1540cy) and MFMA (1242cy) were purely ADDITIVE (2780cy/tile):
// after each barrier both waves of a SIMD read, then both MFMA.  Fix: issue
// each half-tile's fragment reads one phase EARLY so port and MFMA overlap:
//   P0: ds_read(t.ks1->fr1); stage6(t+2); MFMA(fr0)
//   P1: vmcnt(6)+lgkmcnt(0); barrier; ds_read(t+1.ks0->fr0); MFMA(fr1)
// - lgkmcnt(0) BEFORE the barrier: drains this wave's outstanding fragment
//   reads so post-barrier stage writes (other waves, P0 of t+1, into buf
//   (t-1)%3) cannot race them.  Covers both reg sets.
// - vmcnt(6) at P1 of t: newest 6 = stages issued in P0 of t (for t+2) =>
//   t+1's chunks (issued P0 of t-1) proven landed; safe to read t+1.ks0.
// ---------------------------------------------------------------------------
__global__ __launch_bounds__(512, 2) void gemm1_rp(const unsigned short* __restrict__ A2,
                                                   const unsigned short* __restrict__ B2,
                                                   float* __restrict__ C) {
    __shared__ short As_[3][256 * 64];   // 96 KB
    __shared__ short Bs_[3][128 * 64];   // 48 KB

    const int tid = threadIdx.x;
    const int lane = tid & 63;
    const int wave = tid >> 6;       // 0..7
    const int wr = wave >> 1;        // 0..3  (M quarter: 64 rows)
    const int wc = wave & 1;         // 0..1  (N half: 64 cols)

    // XCD-grouped decode: blocks with same bid%8 form one XCD group of 32.
    const int bid = blockIdx.x;
    const int orig = (bid & 7) * 32 + (bid >> 3);
    const int m0 = (orig >> 3) * 256;
    const int n0 = (orig & 7) * 128;

    const int rsel = lane & 15;
    const int part = lane >> 4;      // 0..3

    // fragment LDS addresses (shorts), buffer-relative; row = 64 shorts = 8
    // slots of 16B; swizzle: slot' = slot ^ (row & 7)  (max 2-way bank alias)
    int adrA[4][2], adrB[4][2];
#pragma unroll
    for (int mi = 0; mi < 4; mi++) {
        const int ra = wr * 64 + mi * 16 + rsel;
#pragma unroll
        for (int ks = 0; ks < 2; ks++) {
            const int slot = ks * 4 + part;
            adrA[mi][ks] = ra * 64 + ((slot ^ (ra & 7)) << 3);
        }
    }
#pragma unroll
    for (int ni = 0; ni < 4; ni++) {
        const int rb = wc * 64 + ni * 16 + rsel;
#pragma unroll
        for (int ks = 0; ks < 2; ks++) {
            const int slot = ks * 4 + part;
            adrB[ni][ks] = rb * 64 + ((slot ^ (rb & 7)) << 3);
        }
    }

    // staging: one 8KB chunk (64 rows x 128B) per GLOAD16; global source
    // pre-swizzled so LDS write stays linear.
    const int srow = tid >> 3;                    // 0..63
    const int gslot8 = ((tid & 7) ^ (srow & 7)) << 3;
    const int ldso = wave * 512;                  // wave-uniform (shorts)

#define STAGE_A(buf, q, kcol)                                                     \
    GLOAD16(&A2[(size_t)(m0 + (q) * 64 + srow) * 2048 + (kcol) + gslot8],         \
            &As_[buf][(q) * 4096 + ldso])
#define STAGE_B(buf, b, kcol)                                                     \
    GLOAD16(&B2[(size_t)(n0 + (b) * 64 + srow) * 2048 + (kcol) + gslot8],         \
            &Bs_[buf][(b) * 4096 + ldso])
#define STAGE6(buf, kA, kB)                                                       \
    do {                                                                          \
        STAGE_A(buf, 0, kA); STAGE_A(buf, 1, kA);                                 \
        STAGE_A(buf, 2, kA); STAGE_A(buf, 3, kA);                                 \
        STAGE_B(buf, 0, kB); STAGE_B(buf, 1, kB);                                 \
    } while (0)

    // k -> concat-column maps (uniform within a 64-wide tile)
#define KA_OF(t) (((t) < 16) ? (t) * 64 : (t) * 64 - 1024)
#define KB_OF(t) (((t) < 32) ? (t) * 64 : (t) * 64 - 2048)

    bf16x8 fa0[4], fb0[4], fa1[4], fb1[4];
    f32x4 acc[4][4] = {};

    // ---- prologue: stage tiles 0 and 1 (12 issues); read tile0.ks0 ----
    STAGE6(0, KA_OF(0), KB_OF(0));
    STAGE6(1, KA_OF(1), KB_OF(1));
    asm volatile("s_waitcnt vmcnt(6)" ::: "memory");   // tile 0's 6 landed
    FENCE();
    __builtin_amdgcn_s_barrier();
    FENCE();
#pragma unroll
    for (int mi = 0; mi < 4; mi++)
        fa0[mi] = *reinterpret_cast<const bf16x8*>(&As_[0][adrA[mi][0]]);
#pragma unroll
    for (int ni = 0; ni < 4; ni++)
        fb0[ni] = *reinterpret_cast<const bf16x8*>(&Bs_[0][adrB[ni][0]]);
    FENCE();

    int bufr = 0;   // t % 3

    for (int t = 0; t < 48; ++t) {
        const short* Acur = As_[bufr];
        const short* Bcur = Bs_[bufr];
        const int bnxt = (bufr == 2) ? 0 : bufr + 1;
        const int bstg = (bnxt == 2) ? 0 : bnxt + 1;     // (t+2) % 3
        const int tc = (t + 2 < 48) ? t + 2 : 47;        // clamp tail (dead data)

        // ---------------- P0 ----------------
#pragma unroll
        for (int mi = 0; mi < 4; mi++)
            fa1[mi] = *reinterpret_cast<const bf16x8*>(&Acur[adrA[mi][1]]);
#pragma unroll
        for (int ni = 0; ni < 4; ni++)
            fb1[ni] = *reinterpret_cast<const bf16x8*>(&Bcur[adrB[ni][1]]);
        FENCE();
        STAGE6(bstg, KA_OF(tc), KB_OF(tc));
        FENCE();
        __builtin_amdgcn_s_setprio(1);
#pragma unroll
        for (int mi = 0; mi < 4; mi++)
#pragma unroll
            for (int ni = 0; ni < 4; ni++)
                acc[mi][ni] = __builtin_amdgcn_mfma_f32_16x16x32_bf16(fa0[mi], fb0[ni], acc[mi][ni], 0, 0, 0);
        __builtin_amdgcn_s_setprio(0);
        FENCE();

        // ---------------- P1 ----------------
        asm volatile("s_waitcnt vmcnt(6) lgkmcnt(0)" ::: "memory");
        FENCE();
        __builtin_amdgcn_s_barrier();
        FENCE();
        const short* Anx = As_[bnxt];
        const short* Bnx = Bs_[bnxt];
#pragma unroll
        for (int mi = 0; mi < 4; mi++)
            fa0[mi] = *reinterpret_cast<const bf16x8*>(&Anx[adrA[mi][0]]);
#pragma unroll
        for (int ni = 0; ni < 4; ni++)
            fb0[ni] = *reinterpret_cast<const bf16x8*>(&Bnx[adrB[ni][0]]);
        FENCE();
        __builtin_amdgcn_s_setprio(1);
#pragma unroll
        for (int mi = 0; mi < 4; mi++)
#pragma unroll
            for (int ni = 0; ni < 4; ni++)
                acc[mi][ni] = __builtin_amdgcn_mfma_f32_16x16x32_bf16(fa1[mi], fb1[ni], acc[mi][ni], 0, 0, 0);
        __builtin_amdgcn_s_setprio(0);
        FENCE();

        bufr = bnxt;
    }
#undef STAGE6
#undef STAGE_A
#undef STAGE_B

    asm volatile("s_waitcnt vmcnt(0) lgkmcnt(0)" ::: "memory");   // drain dead tail ops
    FENCE();

    // ---- epilogue: C write (16x16 C/D layout: col=lane&15, row=(lane>>4)*4+r)
    const int col = lane & 15;
    const int quad = lane >> 4;
#pragma unroll
    for (int mi = 0; mi < 4; mi++)
#pragma unroll
        for (int ni = 0; ni < 4; ni++) {
            const int m = m0 + wr * 64 + mi * 16 + quad * 4;
            const int n = n0 + wc * 64 + ni * 16 + col;
            float* dst = &C[(size_t)m * HH + n];
#pragma unroll
            for (int r = 0; r < 4; r++)
                dst[(size_t)r * HH] = acc[mi][ni][r];
        }
}

// ---------------------------------------------------------------------------
// LIF scan — unchanged.
// ---------------------------------------------------------------------------
__global__ __launch_bounds__(256) void lif_scan_flag(const float* __restrict__ xp,
                                                     unsigned short* __restrict__ sp,
                                                     int* __restrict__ count,
                                                     int* __restrict__ list) {
    const int idx = blockIdx.x * 256 + threadIdx.x;
    double v = 0.0;
    bool flg = false;
#pragma unroll 4
    for (int t = 0; t < TT; t++) {
        const double x = (double)xp[(size_t)t * NLANE + idx];
        const double h = v + (x - v) * 0.5;
        const bool s = (h >= 1.0);
        flg |= (fabs(h - 1.0) < DELTA);
        v = s ? 0.0 : h;
        sp[(size_t)t * NLANE + idx] = s ? (unsigned short)F16_ONE : (unsigned short)0;
    }
    if (flg) {
        const int i = atomicAdd(count, 1);
        list[i] = idx;
    }
}

// ---------------------------------------------------------------------------
// Fused exact-recompute — unchanged.
// ---------------------------------------------------------------------------
__global__ __launch_bounds__(1024) void recompute_fused(const float* __restrict__ X,
                                                        const float* __restrict__ W1,
                                                        const int* __restrict__ count,
                                                        const int* __restrict__ list,
                                                        unsigned short* __restrict__ sp) {
    __shared__ double hbuf[TT];
    const int cnt = *count;
    const int wv = threadIdx.x >> 6;   // 0..15
    const int ln = threadIdx.x & 63;

    for (int li = blockIdx.x; li < cnt; li += gridDim.x) {
        const int lane = list[li];
        const int b = lane >> 10;
        const int h = lane & (HH - 1);
        const float4* w4 = reinterpret_cast<const float4*>(W1 + (size_t)h * HH);

        for (int t = wv; t < TT; t += 16) {
            const float4* x4 = reinterpret_cast<const float4*>(X + (size_t)(t * BB + b) * HH);
            double s0 = 0.0, s1 = 0.0, s2 = 0.0, s3 = 0.0;
#pragma unroll
            for (int i = 0; i < 4; i++) {
                const float4 xa = x4[ln + i * 64];
                const float4 wa = w4[ln + i * 64];
                s0 = fma((double)xa.x, (double)wa.x, s0);
                s1 = fma((double)xa.y, (double)wa.y, s1);
                s2 = fma((double)xa.z, (double)wa.z, s2);
                s3 = fma((double)xa.w, (double)wa.w, s3);
            }
            double s = (s0 + s1) + (s2 + s3);
#pragma unroll
            for (int off = 32; off >= 1; off >>= 1)
                s += __shfl_down(s, off);
            if (ln == 0) hbuf[t] = s;
        }
        __syncthreads();

        if (threadIdx.x == 0) {
            double v = 0.0;
            for (int t = 0; t < TT; t++) {
                const double hh = v + (hbuf[t] - v) * 0.5;
                const bool s = (hh >= 1.0);
                v = s ? 0.0 : hh;
                sp[(size_t)t * NLANE + lane] = s ? (unsigned short)F16_ONE : (unsigned short)0;
            }
        }
        __syncthreads();
    }
}

// ---------------------------------------------------------------------------
// GEMM2 — unchanged (128x64 tile, grid-transposed for S m-tile L2 reuse).
// ---------------------------------------------------------------------------
__global__ __launch_bounds__(256) void gemm2_mfma(const unsigned short* __restrict__ S,
                                                  const unsigned short* __restrict__ W,
                                                  float* __restrict__ O) {
    __shared__ short As[128 * 32];   // 8 KB
    __shared__ short Bs[64 * 32];    // 4 KB

    const int tid = threadIdx.x;
    const int lane = tid & 63;
    const int wave = tid >> 6;
    const int m0 = blockIdx.y * 128;   // 64 blocks in M (slow axis)
    const int n0 = blockIdx.x * 64;    // 16 blocks in N (fast axis)
    const int wm = (wave >> 1) * 64;   // {0,64}
    const int wn = (wave & 1) * 32;    // {0,32}

    const int rsel = lane & 15;
    const int part = lane >> 4;

    int adrA[4], adrB[2];
#pragma unroll
    for (int i = 0; i < 4; i++) {
        const int ra = wm + i * 16 + rsel;
        adrA[i] = ra * 32 + (part ^ ((ra >> 1) & 3)) * 8;
    }
#pragma unroll
    for (int i = 0; i < 2; i++) {
        const int rb = wn + i * 16 + rsel;
        adrB[i] = rb * 32 + (part ^ ((rb >> 1) & 3)) * 8;
    }

    f32x4 acc[4][2] = {};

    for (int k0 = 0; k0 < HH; k0 += 32) {
        // 768 chunks: A = 0..511, B = 512..767; wave-uniform sides (64 | 256)
#pragma unroll
        for (int p = 0; p < 3; p++) {
            const int c = tid + p * 256;
            const int cb = wave * 64 + p * 256;
            if (c < 512) {
                const int row = c >> 2;
                const int pslot = c & 3;
                const int pdata = pslot ^ ((row >> 1) & 3);
                GLOAD16(&S[(size_t)(m0 + row) * HH + k0 + pdata * 8], &As[cb * 8]);
            } else {
                const int c2 = c - 512;
                const int row = c2 >> 2;
                const int pslot = c2 & 3;
                const int pdata = pslot ^ ((row >> 1) & 3);
                GLOAD16(&W[(size_t)(n0 + row) * HH + k0 + pdata * 8], &Bs[(cb - 512) * 8]);
            }
        }
        __syncthreads();

        f16x8 a[4], b[2];
#pragma unroll
        for (int mi = 0; mi < 4; mi++)
            a[mi] = *reinterpret_cast<f16x8*>(&As[adrA[mi]]);
#pragma unroll
        for (int ni = 0; ni < 2; ni++)
            b[ni] = *reinterpret_cast<f16x8*>(&Bs[adrB[ni]]);

#pragma unroll
        for (int mi = 0; mi < 4; mi++)
#pragma unroll
            for (int ni = 0; ni < 2; ni++)
                acc[mi][ni] = __builtin_amdgcn_mfma_f32_16x16x32_f16(
                    a[mi], b[ni], acc[mi][ni], 0, 0, 0);

        __syncthreads();
    }

    const int col = lane & 15;
    const int quad = lane >> 4;
#pragma unroll
    for (int mi = 0; mi < 4; mi++)
#pragma unroll
        for (int ni = 0; ni < 2; ni++) {
            const int m = m0 + wm + mi * 16 + quad * 4;
            const int n = n0 + wn + ni * 16 + col;
            float* dst = &O[(size_t)m * HH + n];
#pragma unroll
            for (int r = 0; r < 4; r++)
                dst[(size_t)r * HH] = acc[mi][ni][r];
        }
}

// ---------------------------------------------------------------------------
// Launch (5 dispatches)
// ---------------------------------------------------------------------------
extern "C" void kernel_launch(void* const* d_in, const int* in_sizes, int n_in,
                              void* d_out, int out_size, void* d_ws, size_t ws_size,
                              hipStream_t stream) {
    const float* x  = (const float*)d_in[0];
    const float* W1 = (const float*)d_in[1];
    const float* W2 = (const float*)d_in[2];
    float* out = (float*)d_out;

    char* ws = (char*)d_ws;

    unsigned short* A2   = (unsigned short*)ws;                 // 33.55 MB  [Xhi|Xlo] 8192x2048
    unsigned short* B2   = A2 + (size_t)MM * 2048;              //  4.19 MB  [W1hi|W1lo] 1024x2048
    unsigned short* w2h  = B2 + (size_t)HH * 2048;              //  2.10 MB
    int*            list = (int*)(w2h + (size_t)HH * HH);       // 256 KB
    int*            cnt  = list + NLANE;                        // 4 B
    float*          xp   = (float*)(((uintptr_t)(cnt + 64) + 255) & ~(uintptr_t)255); // 33.55 MB
    unsigned short* sp   = (unsigned short*)ws;  // overlay: spikes reuse A2 after gemm1

    prep_fused<<<10240, 256, 0, stream>>>(x, W1, W2, A2, B2, w2h, cnt);

    gemm1_rp<<<256, 512, 0, stream>>>(A2, B2, xp);

    lif_scan_flag<<<NLANE / 256, 256, 0, stream>>>(xp, sp, cnt, list);

    recompute_fused<<<512, 1024, 0, stream>>>(x, W1, cnt, list, sp);

    dim3 g2(HH / 64, MM / 128);   // x = N (fast): 16 consecutive blocks share an S m-tile
    gemm2_mfma<<<g2, 256, 0, stream>>>(sp, w2h, out);
}

// Round 8
// 210.339 us; speedup vs baseline: 1.2775x; 1.0139x over previous
//
#include <hip/hip_runtime.h>
#include <hip/hip_bf16.h>
#include <stdint.h>

// Problem constants (T=128, B=64, H=1024)
#define TT 128
#define BB 64
#define HH 1024
#define MM (TT * BB)          // 8192 rows of the two GEMMs
#define NLANE (BB * HH)       // 65536 scan lanes
#define DELTA 1.0e-4          // flag band; bf16 3-pass worst-tail ~6e-5 (1.7x margin) — do NOT shrink
#define F16_ONE 0x3C00        // _Float16 1.0

typedef __attribute__((ext_vector_type(8))) short bf16x8;
typedef __attribute__((ext_vector_type(8))) _Float16 f16x8;
typedef __attribute__((ext_vector_type(4))) float f32x4;

// async global->LDS, 16 B per lane; LDS dest = wave-uniform base + lane*16
#define GLOAD16(g, l)                                                        \
    __builtin_amdgcn_global_load_lds(                                        \
        (const __attribute__((address_space(1))) unsigned int*)(g),          \
        (__attribute__((address_space(3))) unsigned int*)(l), 16, 0, 0)

#define FENCE() __builtin_amdgcn_sched_barrier(0)

static __device__ __forceinline__ unsigned short bf16_bits(float f) {
    __hip_bfloat16 b = __float2bfloat16(f);
    return *reinterpret_cast<unsigned short*>(&b);
}
static __device__ __forceinline__ unsigned short f16_bits(float f) {
    _Float16 h = (_Float16)f;
    return *reinterpret_cast<unsigned short*>(&h);
}

// ---------------------------------------------------------------------------
// Fused prep — K-concat layouts (proven):
//   A2[8192][2048] = [Xhi | Xlo] per row;  B2[1024][2048] = [W1hi | W1lo].
// ---------------------------------------------------------------------------
__global__ __launch_bounds__(256) void prep_fused(const float* __restrict__ x,
                                                  const float* __restrict__ W1,
                                                  const float* __restrict__ W2,
                                                  unsigned short* __restrict__ A2,
                                                  unsigned short* __restrict__ B2,
                                                  unsigned short* __restrict__ w2h,
                                                  int* __restrict__ cnt) {
    const int bid = blockIdx.x;
    if (bid == 0 && threadIdx.x == 0) *cnt = 0;

    if (bid < 9216) {
        const bool isX = (bid < 8192);
        const int i = (isX ? bid : bid - 8192) * 256 + threadIdx.x;
        const float4 v4 = reinterpret_cast<const float4*>(isX ? x : W1)[i];
        float v[4] = {v4.x, v4.y, v4.z, v4.w};
        unsigned short hb[4], lb[4];
#pragma unroll
        for (int c = 0; c < 4; c++) {
            hb[c] = bf16_bits(v[c]);
            __hip_bfloat16 hh = *reinterpret_cast<__hip_bfloat16*>(&hb[c]);
            lb[c] = bf16_bits(v[c] - __bfloat162float(hh));
        }
        ushort4* dst = reinterpret_cast<ushort4*>(isX ? A2 : B2);
        const int r = i >> 8;          // row (1024 cols = 256 ushort4)
        const int c4 = i & 255;
        dst[(size_t)r * 512 + c4]       = make_ushort4(hb[0], hb[1], hb[2], hb[3]);
        dst[(size_t)r * 512 + 256 + c4] = make_ushort4(lb[0], lb[1], lb[2], lb[3]);
    } else {
        const int i = (bid - 9216) * 256 + threadIdx.x;
        const float4 v4 = reinterpret_cast<const float4*>(W2)[i];
        float v[4] = {v4.x, v4.y, v4.z, v4.w};
        unsigned short hb[4];
#pragma unroll
        for (int c = 0; c < 4; c++) hb[c] = f16_bits(v[c]);
        reinterpret_cast<ushort4*>(w2h)[i] = make_ushort4(hb[0], hb[1], hb[2], hb[3]);
    }
}

// ---------------------------------------------------------------------------
// GEMM1 — R17: PHYSICAL-K 3-pass register reuse.  R16 post-mortem: LDS port
// (1542 read + ~400 write cyc/tile) is the hard floor; virtual-K re-reads
// fragments per pass (768 KB/wave).  Fix: iterate 32 physical K-tiles (BK=32)
// and run all 3 passes (aH*bH, aH*bL, aL*bH) while {aH,aL,bH,bL} are in
// registers -> 1.5x fewer LDS reads per MFMA, 512 KB/wave total.
//   - LDS row = 128 B = [hi 64B | lo 64B]: the proven 8-slot XOR swizzle
//     (slot' = slot ^ (row&7), conflicts=0) carries over unchanged; staging
//     source swizzle maps slot bit2 -> hi/lo (+1024 shorts).
//   - triple-buffered (A 32K + B 16K per tile = 144 KB); 6 stages/tile;
//     R16's vmcnt(6)+lgkmcnt(0)+barrier ledger unchanged (reads of tile T
//     drain at T+1's lgkmcnt(0); buffer rewritten at T+2: 1-barrier margin).
//   - fragments double-buffered in named register sets (~215 VGPR, 256 budget
//     at 2 waves/SIMD).
// Per-tile/CU: port ~1940 cyc vs MFMA 1549 — balanced; 32 tiles vs 48.
// ---------------------------------------------------------------------------
__global__ __launch_bounds__(512, 2) void gemm1_pk(const unsigned short* __restrict__ A2,
                                                   const unsigned short* __restrict__ B2,
                                                   float* __restrict__ C) {
    __shared__ short As_[3][256 * 64];   // 96 KB  (256 rows x 128B = hi|lo)
    __shared__ short Bs_[3][128 * 64];   // 48 KB

    const int tid = threadIdx.x;
    const int lane = tid & 63;
    const int wave = tid >> 6;       // 0..7
    const int wr = wave >> 1;        // 0..3  (M quarter: 64 rows)
    const int wc = wave & 1;         // 0..1  (N half: 64 cols)

    // XCD-grouped decode: blocks with same bid%8 form one XCD group of 32.
    const int bid = blockIdx.x;
    const int orig = (bid & 7) * 32 + (bid >> 3);
    const int m0 = (orig >> 3) * 256;
    const int n0 = (orig & 7) * 128;

    const int rsel = lane & 15;
    const int part = lane >> 4;      // 0..3

    // fragment LDS addresses (shorts), buffer-relative.  Row = 64 shorts =
    // 8 slots of 16B; logical slot: 0..3 = hi (k-part), 4..7 = lo.
    // physical slot = logical ^ (row & 7)  — proven conflict-free geometry.
    int adrAH[4], adrAL[4], adrBH[4], adrBL[4];
#pragma unroll
    for (int mi = 0; mi < 4; mi++) {
        const int ra = wr * 64 + mi * 16 + rsel;
        adrAH[mi] = ra * 64 + (((part)     ^ (ra & 7)) << 3);
        adrAL[mi] = ra * 64 + (((part + 4) ^ (ra & 7)) << 3);
    }
#pragma unroll
    for (int ni = 0; ni < 4; ni++) {
        const int rb = wc * 64 + ni * 16 + rsel;
        adrBH[ni] = rb * 64 + (((part)     ^ (rb & 7)) << 3);
        adrBL[ni] = rb * 64 + (((part + 4) ^ (rb & 7)) << 3);
    }

    // staging: one 8KB chunk (64 rows x 128B) per GLOAD16 (8 lanes/row).
    // LDS stays linear; global source pre-swizzled:
    //   physical slot p holds logical slot l = p ^ (row&7);
    //   source shorts offset = kc + (l&3)*8 + (l>>2)*1024   (hi / lo select)
    const int srow = tid >> 3;                    // row within 64-row chunk
    const int lsw  = (tid & 7) ^ (srow & 7);      // logical slot for this lane
    const int src_sw = (lsw & 3) * 8 + (lsw >> 2) * 1024;   // shorts
    const int ldso = wave * 512;                  // wave-uniform (shorts)

#define STAGE_A(buf, q, kc)                                                       \
    GLOAD16(&A2[(size_t)(m0 + (q) * 64 + srow) * 2048 + (kc) + src_sw],           \
            &As_[buf][(q) * 4096 + ldso])
#define STAGE_B(buf, b, kc)                                                       \
    GLOAD16(&B2[(size_t)(n0 + (b) * 64 + srow) * 2048 + (kc) + src_sw],           \
            &Bs_[buf][(b) * 4096 + ldso])
#define STAGE6(buf, kc)                                                           \
    do {                                                                          \
        STAGE_A(buf, 0, kc); STAGE_A(buf, 1, kc);                                 \
        STAGE_A(buf, 2, kc); STAGE_A(buf, 3, kc);                                 \
        STAGE_B(buf, 0, kc); STAGE_B(buf, 1, kc);                                 \
    } while (0)

    bf16x8 aH0[4], aL0[4], bH0[4], bL0[4];
    bf16x8 aH1[4], aL1[4], bH1[4], bL1[4];
    f32x4 acc[4][4] = {};

    // ---- prologue: stage tiles 0,1; read tile 0 fragments into set 0 ----
    STAGE6(0, 0);
    STAGE6(1, 32);
    asm volatile("s_waitcnt vmcnt(6)" ::: "memory");   // tile 0's 6 landed
    FENCE();
    __builtin_amdgcn_s_barrier();
    FENCE();
#pragma unroll
    for (int mi = 0; mi < 4; mi++) {
        aH0[mi] = *reinterpret_cast<const bf16x8*>(&As_[0][adrAH[mi]]);
        aL0[mi] = *reinterpret_cast<const bf16x8*>(&As_[0][adrAL[mi]]);
    }
#pragma unroll
    for (int ni = 0; ni < 4; ni++) {
        bH0[ni] = *reinterpret_cast<const bf16x8*>(&Bs_[0][adrBH[ni]]);
        bL0[ni] = *reinterpret_cast<const bf16x8*>(&Bs_[0][adrBL[ni]]);
    }
    FENCE();

    // ---- tile body: uses set U (current tile), loads set L (tile t+1) ----
#define TILE(t_, UAH, UAL, UBH, UBL, LAH, LAL, LBH, LBL)                          \
    do {                                                                          \
        const int t = (t_);                                                       \
        const int bstg = (t + 2) % 3;                                             \
        const int bnxt = (t + 1) % 3;                                             \
        const int tc = (t + 2 < 32) ? t + 2 : 31;   /* clamp tail (dead) */       \
        STAGE6(bstg, tc * 32);                                                    \
        FENCE();                                                                  \
        __builtin_amdgcn_s_setprio(1);                                            \
        _Pragma("unroll")                                                         \
        for (int mi = 0; mi < 4; mi++)                                            \
            _Pragma("unroll")                                                     \
            for (int ni = 0; ni < 4; ni++)                                        \
                acc[mi][ni] = __builtin_amdgcn_mfma_f32_16x16x32_bf16(            \
                    UAH[mi], UBH[ni], acc[mi][ni], 0, 0, 0);                      \
        __builtin_amdgcn_s_setprio(0);                                            \
        asm volatile("s_waitcnt vmcnt(6) lgkmcnt(0)" ::: "memory");               \
        FENCE();                                                                  \
        __builtin_amdgcn_s_barrier();                                             \
        FENCE();                                                                  \
        {                                                                         \
            const short* An = As_[bnxt];                                          \
            const short* Bn = Bs_[bnxt];                                          \
            _Pragma("unroll")                                                     \
            for (int mi = 0; mi < 4; mi++) {                                      \
                LAH[mi] = *reinterpret_cast<const bf16x8*>(&An[adrAH[mi]]);       \
                LAL[mi] = *reinterpret_cast<const bf16x8*>(&An[adrAL[mi]]);       \
            }                                                                     \
            _Pragma("unroll")                                                     \
            for (int ni = 0; ni < 4; ni++) {                                      \
                LBH[ni] = *reinterpret_cast<const bf16x8*>(&Bn[adrBH[ni]]);       \
                LBL[ni] = *reinterpret_cast<const bf16x8*>(&Bn[adrBL[ni]]);       \
            }                                                                     \
        }                                                                         \
        __builtin_amdgcn_s_setprio(1);                                            \
        _Pragma("unroll")                                                         \
        for (int mi = 0; mi < 4; mi++)                                            \
            _Pragma("unroll")                                                     \
            for (int ni = 0; ni < 4; ni++) {                                      \
                acc[mi][ni] = __builtin_amdgcn_mfma_f32_16x16x32_bf16(            \
                    UAH[mi], UBL[ni], acc[mi][ni], 0, 0, 0);                      \
                acc[mi][ni] = __builtin_amdgcn_mfma_f32_16x16x32_bf16(            \
                    UAL[mi], UBH[ni], acc[mi][ni], 0, 0, 0);                      \
            }                                                                     \
        __builtin_amdgcn_s_setprio(0);                                            \
        FENCE();                                                                  \
    } while (0)

    for (int tp = 0; tp < 16; ++tp) {
        TILE(tp * 2,     aH0, aL0, bH0, bL0, aH1, aL1, bH1, bL1);
        TILE(tp * 2 + 1, aH1, aL1, bH1, bL1, aH0, aL0, bH0, bL0);
    }
#undef TILE
#undef STAGE6
#undef STAGE_A
#undef STAGE_B

    asm volatile("s_waitcnt vmcnt(0) lgkmcnt(0)" ::: "memory");   // drain tail
    FENCE();

    // ---- epilogue: C write (16x16 C/D layout: col=lane&15, row=(lane>>4)*4+r)
    const int col = lane & 15;
    const int quad = lane >> 4;
#pragma unroll
    for (int mi = 0; mi < 4; mi++)
#pragma unroll
        for (int ni = 0; ni < 4; ni++) {
            const int m = m0 + wr * 64 + mi * 16 + quad * 4;
            const int n = n0 + wc * 64 + ni * 16 + col;
            float* dst = &C[(size_t)m * HH + n];
#pragma unroll
            for (int r = 0; r < 4; r++)
                dst[(size_t)r * HH] = acc[mi][ni][r];
        }
}

// ---------------------------------------------------------------------------
// LIF scan — unchanged.
// ---------------------------------------------------------------------------
__global__ __launch_bounds__(256) void lif_scan_flag(const float* __restrict__ xp,
                                                     unsigned short* __restrict__ sp,
                                                     int* __restrict__ count,
                                                     int* __restrict__ list) {
    const int idx = blockIdx.x * 256 + threadIdx.x;
    double v = 0.0;
    bool flg = false;
#pragma unroll 4
    for (int t = 0; t < TT; t++) {
        const double x = (double)xp[(size_t)t * NLANE + idx];
        const double h = v + (x - v) * 0.5;
        const bool s = (h >= 1.0);
        flg |= (fabs(h - 1.0) < DELTA);
        v = s ? 0.0 : h;
        sp[(size_t)t * NLANE + idx] = s ? (unsigned short)F16_ONE : (unsigned short)0;
    }
    if (flg) {
        const int i = atomicAdd(count, 1);
        list[i] = idx;
    }
}

// ---------------------------------------------------------------------------
// Fused exact-recompute — unchanged.
// ---------------------------------------------------------------------------
__global__ __launch_bounds__(1024) void recompute_fused(const float* __restrict__ X,
                                                        const float* __restrict__ W1,
                                                        const int* __restrict__ count,
                                                        const int* __restrict__ list,
                                                        unsigned short* __restrict__ sp) {
    __shared__ double hbuf[TT];
    const int cnt = *count;
    const int wv = threadIdx.x >> 6;   // 0..15
    const int ln = threadIdx.x & 63;

    for (int li = blockIdx.x; li < cnt; li += gridDim.x) {
        const int lane = list[li];
        const int b = lane >> 10;
        const int h = lane & (HH - 1);
        const float4* w4 = reinterpret_cast<const float4*>(W1 + (size_t)h * HH);

        for (int t = wv; t < TT; t += 16) {
            const float4* x4 = reinterpret_cast<const float4*>(X + (size_t)(t * BB + b) * HH);
            double s0 = 0.0, s1 = 0.0, s2 = 0.0, s3 = 0.0;
#pragma unroll
            for (int i = 0; i < 4; i++) {
                const float4 xa = x4[ln + i * 64];
                const float4 wa = w4[ln + i * 64];
                s0 = fma((double)xa.x, (double)wa.x, s0);
                s1 = fma((double)xa.y, (double)wa.y, s1);
                s2 = fma((double)xa.z, (double)wa.z, s2);
                s3 = fma((double)xa.w, (double)wa.w, s3);
            }
            double s = (s0 + s1) + (s2 + s3);
#pragma unroll
            for (int off = 32; off >= 1; off >>= 1)
                s += __shfl_down(s, off);
            if (ln == 0) hbuf[t] = s;
        }
        __syncthreads();

        if (threadIdx.x == 0) {
            double v = 0.0;
            for (int t = 0; t < TT; t++) {
                const double hh = v + (hbuf[t] - v) * 0.5;
                const bool s = (hh >= 1.0);
                v = s ? 0.0 : hh;
                sp[(size_t)t * NLANE + lane] = s ? (unsigned short)F16_ONE : (unsigned short)0;
            }
        }
        __syncthreads();
    }
}

// ---------------------------------------------------------------------------
// GEMM2 — unchanged (128x64 tile, grid-transposed for S m-tile L2 reuse).
// ---------------------------------------------------------------------------
__global__ __launch_bounds__(256) void gemm2_mfma(const unsigned short* __restrict__ S,
                                                  const unsigned short* __restrict__ W,
                                                  float* __restrict__ O) {
    __shared__ short As[128 * 32];   // 8 KB
    __shared__ short Bs[64 * 32];    // 4 KB

    const int tid = threadIdx.x;
    const int lane = tid & 63;
    const int wave = tid >> 6;
    const int m0 = blockIdx.y * 128;   // 64 blocks in M (slow axis)
    const int n0 = blockIdx.x * 64;    // 16 blocks in N (fast axis)
    const int wm = (wave >> 1) * 64;   // {0,64}
    const int wn = (wave & 1) * 32;    // {0,32}

    const int rsel = lane & 15;
    const int part = lane >> 4;

    int adrA[4], adrB[2];
#pragma unroll
    for (int i = 0; i < 4; i++) {
        const int ra = wm + i * 16 + rsel;
        adrA[i] = ra * 32 + (part ^ ((ra >> 1) & 3)) * 8;
    }
#pragma unroll
    for (int i = 0; i < 2; i++) {
        const int rb = wn + i * 16 + rsel;
        adrB[i] = rb * 32 + (part ^ ((rb >> 1) & 3)) * 8;
    }

    f32x4 acc[4][2] = {};

    for (int k0 = 0; k0 < HH; k0 += 32) {
        // 768 chunks: A = 0..511, B = 512..767; wave-uniform sides (64 | 256)
#pragma unroll
        for (int p = 0; p < 3; p++) {
            const int c = tid + p * 256;
            const int cb = wave * 64 + p * 256;
            if (c < 512) {
                const int row = c >> 2;
                const int pslot = c & 3;
                const int pdata = pslot ^ ((row >> 1) & 3);
                GLOAD16(&S[(size_t)(m0 + row) * HH + k0 + pdata * 8], &As[cb * 8]);
            } else {
                const int c2 = c - 512;
                const int row = c2 >> 2;
                const int pslot = c2 & 3;
                const int pdata = pslot ^ ((row >> 1) & 3);
                GLOAD16(&W[(size_t)(n0 + row) * HH + k0 + pdata * 8], &Bs[(cb - 512) * 8]);
            }
        }
        __syncthreads();

        f16x8 a[4], b[2];
#pragma unroll
        for (int mi = 0; mi < 4; mi++)
            a[mi] = *reinterpret_cast<f16x8*>(&As[adrA[mi]]);
#pragma unroll
        for (int ni = 0; ni < 2; ni++)
            b[ni] = *reinterpret_cast<f16x8*>(&Bs[adrB[ni]]);

#pragma unroll
        for (int mi = 0; mi < 4; mi++)
#pragma unroll
            for (int ni = 0; ni < 2; ni++)
                acc[mi][ni] = __builtin_amdgcn_mfma_f32_16x16x32_f16(
                    a[mi], b[ni], acc[mi][ni], 0, 0, 0);

        __syncthreads();
    }

    const int col = lane & 15;
    const int quad = lane >> 4;
#pragma unroll
    for (int mi = 0; mi < 4; mi++)
#pragma unroll
        for (int ni = 0; ni < 2; ni++) {
            const int m = m0 + wm + mi * 16 + quad * 4;
            const int n = n0 + wn + ni * 16 + col;
            float* dst = &O[(size_t)m * HH + n];
#pragma unroll
            for (int r = 0; r < 4; r++)
                dst[(size_t)r * HH] = acc[mi][ni][r];
        }
}

// ---------------------------------------------------------------------------
// Launch (5 dispatches)
// ---------------------------------------------------------------------------
extern "C" void kernel_launch(void* const* d_in, const int* in_sizes, int n_in,
                              void* d_out, int out_size, void* d_ws, size_t ws_size,
                              hipStream_t stream) {
    const float* x  = (const float*)d_in[0];
    const float* W1 = (const float*)d_in[1];
    const float* W2 = (const float*)d_in[2];
    float* out = (float*)d_out;

    char* ws = (char*)d_ws;

    unsigned short* A2   = (unsigned short*)ws;                 // 33.55 MB  [Xhi|Xlo] 8192x2048
    unsigned short* B2   = A2 + (size_t)MM * 2048;              //  4.19 MB  [W1hi|W1lo] 1024x2048
    unsigned short* w2h  = B2 + (size_t)HH * 2048;              //  2.10 MB
    int*            list = (int*)(w2h + (size_t)HH * HH);       // 256 KB
    int*            cnt  = list + NLANE;                        // 4 B
    float*          xp   = (float*)(((uintptr_t)(cnt + 64) + 255) & ~(uintptr_t)255); // 33.55 MB
    unsigned short* sp   = (unsigned short*)ws;  // overlay: spikes reuse A2 after gemm1

    prep_fused<<<10240, 256, 0, stream>>>(x, W1, W2, A2, B2, w2h, cnt);

    gemm1_pk<<<256, 512, 0, stream>>>(A2, B2, xp);

    lif_scan_flag<<<NLANE / 256, 256, 0, stream>>>(xp, sp, cnt, list);

    recompute_fused<<<512, 1024, 0, stream>>>(x, W1, cnt, list, sp);

    dim3 g2(HH / 64, MM / 128);   // x = N (fast): 16 consecutive blocks share an S m-tile
    gemm2_mfma<<<g2, 256, 0, stream>>>(sp, w2h, out);
}

// Round 9
// 208.541 us; speedup vs baseline: 1.2886x; 1.0086x over previous
//
#include <hip/hip_runtime.h>
#include <hip/hip_bf16.h>
#include <stdint.h>

// Problem constants (T=128, B=64, H=1024)
#define TT 128
#define BB 64
#define HH 1024
#define MM (TT * BB)          // 8192 rows of the two GEMMs
#define NLANE (BB * HH)       // 65536 scan lanes
#define DELTA 1.0e-4          // flag band; bf16 3-pass worst-tail ~6e-5 (1.7x margin) — do NOT shrink
#define F16_ONE 0x3C00        // _Float16 1.0

typedef __attribute__((ext_vector_type(8))) short bf16x8;
typedef __attribute__((ext_vector_type(8))) _Float16 f16x8;
typedef __attribute__((ext_vector_type(4))) float f32x4;

// async global->LDS, 16 B per lane; LDS dest = wave-uniform base + lane*16
#define GLOAD16(g, l)                                                        \
    __builtin_amdgcn_global_load_lds(                                        \
        (const __attribute__((address_space(1))) unsigned int*)(g),          \
        (__attribute__((address_space(3))) unsigned int*)(l), 16, 0, 0)

#define FENCE() __builtin_amdgcn_sched_barrier(0)

static __device__ __forceinline__ unsigned short bf16_bits(float f) {
    __hip_bfloat16 b = __float2bfloat16(f);
    return *reinterpret_cast<unsigned short*>(&b);
}
static __device__ __forceinline__ unsigned short f16_bits(float f) {
    _Float16 h = (_Float16)f;
    return *reinterpret_cast<unsigned short*>(&h);
}

// ---------------------------------------------------------------------------
// Fused prep — K-concat layouts (proven):
//   A2[8192][2048] = [Xhi | Xlo] per row;  B2[1024][2048] = [W1hi | W1lo].
// ---------------------------------------------------------------------------
__global__ __launch_bounds__(256) void prep_fused(const float* __restrict__ x,
                                                  const float* __restrict__ W1,
                                                  const float* __restrict__ W2,
                                                  unsigned short* __restrict__ A2,
                                                  unsigned short* __restrict__ B2,
                                                  unsigned short* __restrict__ w2h,
                                                  int* __restrict__ cnt) {
    const int bid = blockIdx.x;
    if (bid == 0 && threadIdx.x == 0) *cnt = 0;

    if (bid < 9216) {
        const bool isX = (bid < 8192);
        const int i = (isX ? bid : bid - 8192) * 256 + threadIdx.x;
        const float4 v4 = reinterpret_cast<const float4*>(isX ? x : W1)[i];
        float v[4] = {v4.x, v4.y, v4.z, v4.w};
        unsigned short hb[4], lb[4];
#pragma unroll
        for (int c = 0; c < 4; c++) {
            hb[c] = bf16_bits(v[c]);
            __hip_bfloat16 hh = *reinterpret_cast<__hip_bfloat16*>(&hb[c]);
            lb[c] = bf16_bits(v[c] - __bfloat162float(hh));
        }
        ushort4* dst = reinterpret_cast<ushort4*>(isX ? A2 : B2);
        const int r = i >> 8;          // row (1024 cols = 256 ushort4)
        const int c4 = i & 255;
        dst[(size_t)r * 512 + c4]       = make_ushort4(hb[0], hb[1], hb[2], hb[3]);
        dst[(size_t)r * 512 + 256 + c4] = make_ushort4(lb[0], lb[1], lb[2], lb[3]);
    } else {
        const int i = (bid - 9216) * 256 + threadIdx.x;
        const float4 v4 = reinterpret_cast<const float4*>(W2)[i];
        float v[4] = {v4.x, v4.y, v4.z, v4.w};
        unsigned short hb[4];
#pragma unroll
        for (int c = 0; c < 4; c++) hb[c] = f16_bits(v[c]);
        reinterpret_cast<ushort4*>(w2h)[i] = make_ushort4(hb[0], hb[1], hb[2], hb[3]);
    }
}

// ---------------------------------------------------------------------------
// GEMM1 — R18: R17 (physical-K 3-pass register reuse, triple-buffered LDS,
// BK=32, 32 tiles) + FORCED READ/MFMA INTERLEAVE.  R17 post-mortem: MFMA
// (1535cy) and LDS port (~1926cy) were ADDITIVE per tile (3772cy measured) —
// lockstep waves issue all 16 ds_reads, then all MFMAs; in-order issue +
// queue backpressure serializes the pipes.  Fix: ONE post-barrier scheduling
// region containing all 48 MFMAs (current tile) + 16 ds_reads (next tile),
// forced to {1 DS_READ, 3 MFMA} x 16 via sched_group_barrier (T19, applied
// in its correct regime: measured pipe serialization).
//   Per tile: STAGE6(t+2) -> lgkmcnt(0)+vmcnt(6) -> ONE barrier ->
//             interleaved [reads(t+1) + MFMA(t)] under setprio(1).
//   Ledger (re-derived): vmcnt(6) at t has 12 outstanding (stages t+1, t+2);
//   waits exactly for stages(t+1) = buffer read post-barrier.  Old-read vs
//   new-write: reads of buf b at tile t drained by t+1's pre-barrier
//   lgkmcnt(0); that buffer rewritten at t+2 after the barrier — safe.
//   Tail reads are dead but in-bounds; drained by final vmcnt(0)+lgkmcnt(0).
// ---------------------------------------------------------------------------
__global__ __launch_bounds__(512, 2) void gemm1_il(const unsigned short* __restrict__ A2,
                                                   const unsigned short* __restrict__ B2,
                                                   float* __restrict__ C) {
    __shared__ short As_[3][256 * 64];   // 96 KB  (256 rows x 128B = hi|lo)
    __shared__ short Bs_[3][128 * 64];   // 48 KB

    const int tid = threadIdx.x;
    const int lane = tid & 63;
    const int wave = tid >> 6;       // 0..7
    const int wr = wave >> 1;        // 0..3  (M quarter: 64 rows)
    const int wc = wave & 1;         // 0..1  (N half: 64 cols)

    // XCD-grouped decode: blocks with same bid%8 form one XCD group of 32.
    const int bid = blockIdx.x;
    const int orig = (bid & 7) * 32 + (bid >> 3);
    const int m0 = (orig >> 3) * 256;
    const int n0 = (orig & 7) * 128;

    const int rsel = lane & 15;
    const int part = lane >> 4;      // 0..3

    // fragment LDS addresses (shorts), buffer-relative.  Row = 64 shorts =
    // 8 slots of 16B; logical slot: 0..3 = hi (k-part), 4..7 = lo.
    // physical slot = logical ^ (row & 7)  — proven conflict-free geometry.
    int adrAH[4], adrAL[4], adrBH[4], adrBL[4];
#pragma unroll
    for (int mi = 0; mi < 4; mi++) {
        const int ra = wr * 64 + mi * 16 + rsel;
        adrAH[mi] = ra * 64 + (((part)     ^ (ra & 7)) << 3);
        adrAL[mi] = ra * 64 + (((part + 4) ^ (ra & 7)) << 3);
    }
#pragma unroll
    for (int ni = 0; ni < 4; ni++) {
        const int rb = wc * 64 + ni * 16 + rsel;
        adrBH[ni] = rb * 64 + (((part)     ^ (rb & 7)) << 3);
        adrBL[ni] = rb * 64 + (((part + 4) ^ (rb & 7)) << 3);
    }

    // staging: one 8KB chunk (64 rows x 128B) per GLOAD16 (8 lanes/row).
    // LDS stays linear; global source pre-swizzled:
    //   physical slot p holds logical slot l = p ^ (row&7);
    //   source shorts offset = kc + (l&3)*8 + (l>>2)*1024   (hi / lo select)
    const int srow = tid >> 3;                    // row within 64-row chunk
    const int lsw  = (tid & 7) ^ (srow & 7);      // logical slot for this lane
    const int src_sw = (lsw & 3) * 8 + (lsw >> 2) * 1024;   // shorts
    const int ldso = wave * 512;                  // wave-uniform (shorts)

#define STAGE_A(buf, q, kc)                                                       \
    GLOAD16(&A2[(size_t)(m0 + (q) * 64 + srow) * 2048 + (kc) + src_sw],           \
            &As_[buf][(q) * 4096 + ldso])
#define STAGE_B(buf, b, kc)                                                       \
    GLOAD16(&B2[(size_t)(n0 + (b) * 64 + srow) * 2048 + (kc) + src_sw],           \
            &Bs_[buf][(b) * 4096 + ldso])
#define STAGE6(buf, kc)                                                           \
    do {                                                                          \
        STAGE_A(buf, 0, kc); STAGE_A(buf, 1, kc);                                 \
        STAGE_A(buf, 2, kc); STAGE_A(buf, 3, kc);                                 \
        STAGE_B(buf, 0, kc); STAGE_B(buf, 1, kc);                                 \
    } while (0)

    bf16x8 aH0[4], aL0[4], bH0[4], bL0[4];
    bf16x8 aH1[4], aL1[4], bH1[4], bL1[4];
    f32x4 acc[4][4] = {};

    // ---- prologue: stage tiles 0,1; read tile 0 fragments into set 0 ----
    STAGE6(0, 0);
    STAGE6(1, 32);
    asm volatile("s_waitcnt vmcnt(6)" ::: "memory");   // tile 0's 6 landed
    FENCE();
    __builtin_amdgcn_s_barrier();
    FENCE();
#pragma unroll
    for (int mi = 0; mi < 4; mi++) {
        aH0[mi] = *reinterpret_cast<const bf16x8*>(&As_[0][adrAH[mi]]);
        aL0[mi] = *reinterpret_cast<const bf16x8*>(&As_[0][adrAL[mi]]);
    }
#pragma unroll
    for (int ni = 0; ni < 4; ni++) {
        bH0[ni] = *reinterpret_cast<const bf16x8*>(&Bs_[0][adrBH[ni]]);
        bL0[ni] = *reinterpret_cast<const bf16x8*>(&Bs_[0][adrBL[ni]]);
    }
    FENCE();

    // ---- tile body: MFMAs on set U (tile t), reads tile t+1 into set L,
    //      both in ONE region, forced {1 DS_READ, 3 MFMA} x 16 ----
#define TILE(t_, UAH, UAL, UBH, UBL, LAH, LAL, LBH, LBL)                          \
    do {                                                                          \
        const int t = (t_);                                                       \
        const int bstg = (t + 2) % 3;                                             \
        const int bnxt = (t + 1) % 3;                                             \
        const int tc = (t + 2 < 32) ? t + 2 : 31;   /* clamp tail (dead) */       \
        STAGE6(bstg, tc * 32);                                                    \
        asm volatile("s_waitcnt vmcnt(6) lgkmcnt(0)" ::: "memory");               \
        FENCE();                                                                  \
        __builtin_amdgcn_s_barrier();                                             \
        FENCE();                                                                  \
        __builtin_amdgcn_s_setprio(1);                                            \
        {                                                                         \
            const short* An = As_[bnxt];                                          \
            const short* Bn = Bs_[bnxt];                                          \
            _Pragma("unroll")                                                     \
            for (int mi = 0; mi < 4; mi++) {                                      \
                LAH[mi] = *reinterpret_cast<const bf16x8*>(&An[adrAH[mi]]);       \
                LAL[mi] = *reinterpret_cast<const bf16x8*>(&An[adrAL[mi]]);       \
            }                                                                     \
            _Pragma("unroll")                                                     \
            for (int ni = 0; ni < 4; ni++) {                                      \
                LBH[ni] = *reinterpret_cast<const bf16x8*>(&Bn[adrBH[ni]]);       \
                LBL[ni] = *reinterpret_cast<const bf16x8*>(&Bn[adrBL[ni]]);       \
            }                                                                     \
        }                                                                         \
        _Pragma("unroll")                                                         \
        for (int mi = 0; mi < 4; mi++)                                            \
            _Pragma("unroll")                                                     \
            for (int ni = 0; ni < 4; ni++)                                        \
                acc[mi][ni] = __builtin_amdgcn_mfma_f32_16x16x32_bf16(            \
                    UAH[mi], UBH[ni], acc[mi][ni], 0, 0, 0);                      \
        _Pragma("unroll")                                                         \
        for (int mi = 0; mi < 4; mi++)                                            \
            _Pragma("unroll")                                                     \
            for (int ni = 0; ni < 4; ni++) {                                      \
                acc[mi][ni] = __builtin_amdgcn_mfma_f32_16x16x32_bf16(            \
                    UAH[mi], UBL[ni], acc[mi][ni], 0, 0, 0);                      \
                acc[mi][ni] = __builtin_amdgcn_mfma_f32_16x16x32_bf16(            \
                    UAL[mi], UBH[ni], acc[mi][ni], 0, 0, 0);                      \
            }                                                                     \
        _Pragma("unroll")                                                         \
        for (int g = 0; g < 16; ++g) {                                            \
            __builtin_amdgcn_sched_group_barrier(0x100, 1, 0); /* 1 DS_READ */    \
            __builtin_amdgcn_sched_group_barrier(0x008, 3, 0); /* 3 MFMA    */    \
        }                                                                         \
        __builtin_amdgcn_s_setprio(0);                                            \
        FENCE();                                                                  \
    } while (0)

    for (int tp = 0; tp < 16; ++tp) {
        TILE(tp * 2,     aH0, aL0, bH0, bL0, aH1, aL1, bH1, bL1);
        TILE(tp * 2 + 1, aH1, aL1, bH1, bL1, aH0, aL0, bH0, bL0);
    }
#undef TILE
#undef STAGE6
#undef STAGE_A
#undef STAGE_B

    asm volatile("s_waitcnt vmcnt(0) lgkmcnt(0)" ::: "memory");   // drain tail
    FENCE();

    // ---- epilogue: C write (16x16 C/D layout: col=lane&15, row=(lane>>4)*4+r)
    const int col = lane & 15;
    const int quad = lane >> 4;
#pragma unroll
    for (int mi = 0; mi < 4; mi++)
#pragma unroll
        for (int ni = 0; ni < 4; ni++) {
            const int m = m0 + wr * 64 + mi * 16 + quad * 4;
            const int n = n0 + wc * 64 + ni * 16 + col;
            float* dst = &C[(size_t)m * HH + n];
#pragma unroll
            for (int r = 0; r < 4; r++)
                dst[(size_t)r * HH] = acc[mi][ni][r];
        }
}

// ---------------------------------------------------------------------------
// LIF scan — unchanged.
// ---------------------------------------------------------------------------
__global__ __launch_bounds__(256) void lif_scan_flag(const float* __restrict__ xp,
                                                     unsigned short* __restrict__ sp,
                                                     int* __restrict__ count,
                                                     int* __restrict__ list) {
    const int idx = blockIdx.x * 256 + threadIdx.x;
    double v = 0.0;
    bool flg = false;
#pragma unroll 4
    for (int t = 0; t < TT; t++) {
        const double x = (double)xp[(size_t)t * NLANE + idx];
        const double h = v + (x - v) * 0.5;
        const bool s = (h >= 1.0);
        flg |= (fabs(h - 1.0) < DELTA);
        v = s ? 0.0 : h;
        sp[(size_t)t * NLANE + idx] = s ? (unsigned short)F16_ONE : (unsigned short)0;
    }
    if (flg) {
        const int i = atomicAdd(count, 1);
        list[i] = idx;
    }
}

// ---------------------------------------------------------------------------
// Fused exact-recompute — unchanged.
// ---------------------------------------------------------------------------
__global__ __launch_bounds__(1024) void recompute_fused(const float* __restrict__ X,
                                                        const float* __restrict__ W1,
                                                        const int* __restrict__ count,
                                                        const int* __restrict__ list,
                                                        unsigned short* __restrict__ sp) {
    __shared__ double hbuf[TT];
    const int cnt = *count;
    const int wv = threadIdx.x >> 6;   // 0..15
    const int ln = threadIdx.x & 63;

    for (int li = blockIdx.x; li < cnt; li += gridDim.x) {
        const int lane = list[li];
        const int b = lane >> 10;
        const int h = lane & (HH - 1);
        const float4* w4 = reinterpret_cast<const float4*>(W1 + (size_t)h * HH);

        for (int t = wv; t < TT; t += 16) {
            const float4* x4 = reinterpret_cast<const float4*>(X + (size_t)(t * BB + b) * HH);
            double s0 = 0.0, s1 = 0.0, s2 = 0.0, s3 = 0.0;
#pragma unroll
            for (int i = 0; i < 4; i++) {
                const float4 xa = x4[ln + i * 64];
                const float4 wa = w4[ln + i * 64];
                s0 = fma((double)xa.x, (double)wa.x, s0);
                s1 = fma((double)xa.y, (double)wa.y, s1);
                s2 = fma((double)xa.z, (double)wa.z, s2);
                s3 = fma((double)xa.w, (double)wa.w, s3);
            }
            double s = (s0 + s1) + (s2 + s3);
#pragma unroll
            for (int off = 32; off >= 1; off >>= 1)
                s += __shfl_down(s, off);
            if (ln == 0) hbuf[t] = s;
        }
        __syncthreads();

        if (threadIdx.x == 0) {
            double v = 0.0;
            for (int t = 0; t < TT; t++) {
                const double hh = v + (hbuf[t] - v) * 0.5;
                const bool s = (hh >= 1.0);
                v = s ? 0.0 : hh;
                sp[(size_t)t * NLANE + lane] = s ? (unsigned short)F16_ONE : (unsigned short)0;
            }
        }
        __syncthreads();
    }
}

// ---------------------------------------------------------------------------
// GEMM2 — unchanged (128x64 tile, grid-transposed for S m-tile L2 reuse).
// ---------------------------------------------------------------------------
__global__ __launch_bounds__(256) void gemm2_mfma(const unsigned short* __restrict__ S,
                                                  const unsigned short* __restrict__ W,
                                                  float* __restrict__ O) {
    __shared__ short As[128 * 32];   // 8 KB
    __shared__ short Bs[64 * 32];    // 4 KB

    const int tid = threadIdx.x;
    const int lane = tid & 63;
    const int wave = tid >> 6;
    const int m0 = blockIdx.y * 128;   // 64 blocks in M (slow axis)
    const int n0 = blockIdx.x * 64;    // 16 blocks in N (fast axis)
    const int wm = (wave >> 1) * 64;   // {0,64}
    const int wn = (wave & 1) * 32;    // {0,32}

    const int rsel = lane & 15;
    const int part = lane >> 4;

    int adrA[4], adrB[2];
#pragma unroll
    for (int i = 0; i < 4; i++) {
        const int ra = wm + i * 16 + rsel;
        adrA[i] = ra * 32 + (part ^ ((ra >> 1) & 3)) * 8;
    }
#pragma unroll
    for (int i = 0; i < 2; i++) {
        const int rb = wn + i * 16 + rsel;
        adrB[i] = rb * 32 + (part ^ ((rb >> 1) & 3)) * 8;
    }

    f32x4 acc[4][2] = {};

    for (int k0 = 0; k0 < HH; k0 += 32) {
        // 768 chunks: A = 0..511, B = 512..767; wave-uniform sides (64 | 256)
#pragma unroll
        for (int p = 0; p < 3; p++) {
            const int c = tid + p * 256;
            const int cb = wave * 64 + p * 256;
            if (c < 512) {
                const int row = c >> 2;
                const int pslot = c & 3;
                const int pdata = pslot ^ ((row >> 1) & 3);
                GLOAD16(&S[(size_t)(m0 + row) * HH + k0 + pdata * 8], &As[cb * 8]);
            } else {
                const int c2 = c - 512;
                const int row = c2 >> 2;
                const int pslot = c2 & 3;
                const int pdata = pslot ^ ((row >> 1) & 3);
                GLOAD16(&W[(size_t)(n0 + row) * HH + k0 + pdata * 8], &Bs[(cb - 512) * 8]);
            }
        }
        __syncthreads();

        f16x8 a[4], b[2];
#pragma unroll
        for (int mi = 0; mi < 4; mi++)
            a[mi] = *reinterpret_cast<f16x8*>(&As[adrA[mi]]);
#pragma unroll
        for (int ni = 0; ni < 2; ni++)
            b[ni] = *reinterpret_cast<f16x8*>(&Bs[adrB[ni]]);

#pragma unroll
        for (int mi = 0; mi < 4; mi++)
#pragma unroll
            for (int ni = 0; ni < 2; ni++)
                acc[mi][ni] = __builtin_amdgcn_mfma_f32_16x16x32_f16(
                    a[mi], b[ni], acc[mi][ni], 0, 0, 0);

        __syncthreads();
    }

    const int col = lane & 15;
    const int quad = lane >> 4;
#pragma unroll
    for (int mi = 0; mi < 4; mi++)
#pragma unroll
        for (int ni = 0; ni < 2; ni++) {
            const int m = m0 + wm + mi * 16 + quad * 4;
            const int n = n0 + wn + ni * 16 + col;
            float* dst = &O[(size_t)m * HH + n];
#pragma unroll
            for (int r = 0; r < 4; r++)
                dst[(size_t)r * HH] = acc[mi][ni][r];
        }
}

// ---------------------------------------------------------------------------
// Launch (5 dispatches)
// ---------------------------------------------------------------------------
extern "C" void kernel_launch(void* const* d_in, const int* in_sizes, int n_in,
                              void* d_out, int out_size, void* d_ws, size_t ws_size,
                              hipStream_t stream) {
    const float* x  = (const float*)d_in[0];
    const float* W1 = (const float*)d_in[1];
    const float* W2 = (const float*)d_in[2];
    float* out = (float*)d_out;

    char* ws = (char*)d_ws;

    unsigned short* A2   = (unsigned short*)ws;                 // 33.55 MB  [Xhi|Xlo] 8192x2048
    unsigned short* B2   = A2 + (size_t)MM * 2048;              //  4.19 MB  [W1hi|W1lo] 1024x2048
    unsigned short* w2h  = B2 + (size_t)HH * 2048;              //  2.10 MB
    int*            list = (int*)(w2h + (size_t)HH * HH);       // 256 KB
    int*            cnt  = list + NLANE;                        // 4 B
    float*          xp   = (float*)(((uintptr_t)(cnt + 64) + 255) & ~(uintptr_t)255); // 33.55 MB
    unsigned short* sp   = (unsigned short*)ws;  // overlay: spikes reuse A2 after gemm1

    prep_fused<<<10240, 256, 0, stream>>>(x, W1, W2, A2, B2, w2h, cnt);

    gemm1_il<<<256, 512, 0, stream>>>(A2, B2, xp);

    lif_scan_flag<<<NLANE / 256, 256, 0, stream>>>(xp, sp, cnt, list);

    recompute_fused<<<512, 1024, 0, stream>>>(x, W1, cnt, list, sp);

    dim3 g2(HH / 64, MM / 128);   // x = N (fast): 16 consecutive blocks share an S m-tile
    gemm2_mfma<<<g2, 256, 0, stream>>>(sp, w2h, out);
}